// Round 4
// baseline (1149.907 us; speedup 1.0000x reference)
//
#include <hip/hip_runtime.h>
#include <math.h>

#define BB 512
#define HH 512
#define KK 6
#define TT 60
#define OO 2
#define H2 1024
#define TO 120
#define RFP 520   // padded LDS row stride (bf16 elems)

typedef __bf16 bf16x8 __attribute__((ext_vector_type(8)));
typedef float  f32x4  __attribute__((ext_vector_type(4)));

__device__ __forceinline__ float bf2f(unsigned short u) {
    union { unsigned int i; float f; } v; v.i = ((unsigned int)u) << 16; return v.f;
}
__device__ __forceinline__ unsigned short f2bf(float f) {
    union { float f; unsigned int i; } v; v.f = f;
    unsigned int b = v.i;
    return (unsigned short)((b + 0x7FFFu + ((b >> 16) & 1u)) >> 16); // RNE
}
__device__ __forceinline__ float gelu_exact(float x) {
    return 0.5f * x * (1.0f + erff(x * 0.70710678118654752f));
}

struct F8 { float v[8]; };
__device__ __forceinline__ F8 load8f(const float* p) {
    F8 r;
    float4 a = *(const float4*)p;
    float4 b = *(const float4*)(p + 4);
    r.v[0] = a.x; r.v[1] = a.y; r.v[2] = a.z; r.v[3] = a.w;
    r.v[4] = b.x; r.v[5] = b.y; r.v[6] = b.z; r.v[7] = b.w;
    return r;
}
__device__ __forceinline__ F8 load8b(const unsigned short* p) {
    ushort4 a = *(const ushort4*)p;
    ushort4 b = *(const ushort4*)(p + 4);
    F8 r;
    r.v[0] = bf2f(a.x); r.v[1] = bf2f(a.y); r.v[2] = bf2f(a.z); r.v[3] = bf2f(a.w);
    r.v[4] = bf2f(b.x); r.v[5] = bf2f(b.y); r.v[6] = bf2f(b.z); r.v[7] = bf2f(b.w);
    return r;
}

// ---------------- transpose Wr1 (K,H,H) fp32 -> Wr1T (K,H,H) bf16 [n][f] ----------------
__global__ void k_transpose(const float* __restrict__ in, unsigned short* __restrict__ out) {
    __shared__ unsigned short t[32][33];
    int k = blockIdx.z;
    int f0 = blockIdx.x * 32, n0 = blockIdx.y * 32;
    int r = threadIdx.x / 32, c = threadIdx.x % 32;
    const float* src = in + k * HH * HH;
    unsigned short* dst = out + k * HH * HH;
#pragma unroll
    for (int i = 0; i < 4; ++i)
        t[r + 8 * i][c] = f2bf(src[(f0 + r + 8 * i) * HH + n0 + c]);
    __syncthreads();
#pragma unroll
    for (int i = 0; i < 4; ++i)
        dst[(n0 + r + 8 * i) * HH + f0 + c] = t[c][r + 8 * i];
}

// --------- GEMM: C(512x512 bf16) = [gelu](A @ B + bias) ---------
// ADT: 0 = bf16 A source, 1 = fp32. Weights/bias always fp32 (model inputs).
// CONCAT: A = [A0|A1|A2] along columns (each 512 wide, fp32).
template <int ADT, bool CONCAT, bool GELU>
__launch_bounds__(256)
__global__ void k_gemm(const void* __restrict__ A0, const void* __restrict__ A1,
                       const void* __restrict__ A2, const float* __restrict__ Bm,
                       const float* __restrict__ bias, unsigned short* __restrict__ C,
                       int Kd) {
    __shared__ float As[64][17];
    __shared__ float Bs[16][65];
    int tid = threadIdx.x;
    int tx = tid % 16, ty = tid / 16;
    int bm = blockIdx.x * 64, bn = blockIdx.y * 64;
    float acc[4][4] = {};
    for (int k0 = 0; k0 < Kd; k0 += 16) {
        {
            int r = tid / 4, cc = (tid % 4) * 4;
            int c = k0 + cc;
            float a4[4];
            if (CONCAT) {
                const float* src = (c < HH) ? (const float*)A0 : (c < 2 * HH) ? (const float*)A1 : (const float*)A2;
                int cm = (c < HH) ? c : (c < 2 * HH) ? (c - HH) : (c - 2 * HH);
                float4 v = *(const float4*)(src + (bm + r) * HH + cm);
                a4[0] = v.x; a4[1] = v.y; a4[2] = v.z; a4[3] = v.w;
            } else if (ADT == 1) {
                float4 v = *(const float4*)((const float*)A0 + (bm + r) * Kd + c);
                a4[0] = v.x; a4[1] = v.y; a4[2] = v.z; a4[3] = v.w;
            } else {
                ushort4 v = *(const ushort4*)((const unsigned short*)A0 + (bm + r) * Kd + c);
                a4[0] = bf2f(v.x); a4[1] = bf2f(v.y); a4[2] = bf2f(v.z); a4[3] = bf2f(v.w);
            }
            As[r][cc] = a4[0]; As[r][cc + 1] = a4[1]; As[r][cc + 2] = a4[2]; As[r][cc + 3] = a4[3];
        }
        {
            int r = tid / 16, cc = (tid % 16) * 4;
            float4 v = *(const float4*)(Bm + (k0 + r) * HH + bn + cc);
            Bs[r][cc] = v.x; Bs[r][cc + 1] = v.y; Bs[r][cc + 2] = v.z; Bs[r][cc + 3] = v.w;
        }
        __syncthreads();
#pragma unroll
        for (int kk = 0; kk < 16; ++kk) {
            float a[4], bv[4];
#pragma unroll
            for (int i = 0; i < 4; ++i) a[i] = As[ty * 4 + i][kk];
#pragma unroll
            for (int j = 0; j < 4; ++j) bv[j] = Bs[kk][tx * 4 + j];
#pragma unroll
            for (int i = 0; i < 4; ++i)
#pragma unroll
                for (int j = 0; j < 4; ++j)
                    acc[i][j] = fmaf(a[i], bv[j], acc[i][j]);
        }
        __syncthreads();
    }
#pragma unroll
    for (int i = 0; i < 4; ++i) {
        int row = bm + ty * 4 + i;
#pragma unroll
        for (int j = 0; j < 4; ++j) {
            int col = bn + tx * 4 + j;
            float v = acc[i][j] + bias[col];
            if (GELU) v = gelu_exact(v);
            C[row * HH + col] = f2bf(v);
        }
    }
}

// ---------------- fused per-(b,k) kernel ----------------
__launch_bounds__(256, 2)
__global__ void k_fused(
    const unsigned short* __restrict__ ctx, const unsigned short* __restrict__ attn,
    const float* __restrict__ mq,
    const float* __restrict__ Wk1, const float* __restrict__ bk1,
    const float* __restrict__ Wk2, const float* __restrict__ bk2,
    const float* __restrict__ Wt,  const float* __restrict__ bt,
    const float* __restrict__ lng, const float* __restrict__ lnb,
    const unsigned short* __restrict__ Wr1T, const float* __restrict__ br1,
    const float* __restrict__ Wr2, const float* __restrict__ br2,
    const float* __restrict__ Wf1, const float* __restrict__ bf1,
    const float* __restrict__ Wf2, const float* __restrict__ bf2v,
    float* __restrict__ pred_out, float* __restrict__ conf_out)
{
    __shared__ __align__(16) unsigned short rf[64 * RFP];
    __shared__ float mf[HH];
    __shared__ float hbuf[H2];
    __shared__ float coarse[TO];
    __shared__ float c1[64];
    __shared__ float po[64][2];

    const int tid = threadIdx.x;
    const int b = blockIdx.x / KK;
    const int k = blockIdx.x % KK;
    const int w = tid >> 6;
    const int ln = tid & 63;

    const unsigned short* ctxb = ctx + b * HH;
    const unsigned short* attb = attn + b * HH;

    // ---- Phase A: stage mode_features row, zero po ----
    for (int i = tid; i < HH; i += 256)
        mf[i] = bf2f(ctxb[i]) + mq[k * HH + i];
    if (tid < 128) ((float*)po)[tid] = 0.f;
    __syncthreads();

    // ---- Phase B: h = gelu(mf @ Wk1[k] + bk1[k]) ----
    {
        const float* wk = Wk1 + k * HH * H2;
        const int n0 = tid * 4;
        float a0 = 0.f, a1 = 0.f, a2 = 0.f, a3 = 0.f;
#pragma unroll 4
        for (int f = 0; f < HH; ++f) {
            float a = mf[f];
            float4 wv = *(const float4*)(wk + f * H2 + n0);
            a0 = fmaf(a, wv.x, a0);
            a1 = fmaf(a, wv.y, a1);
            a2 = fmaf(a, wv.z, a2);
            a3 = fmaf(a, wv.w, a3);
        }
        hbuf[n0]     = gelu_exact(a0 + bk1[k * H2 + n0]);
        hbuf[n0 + 1] = gelu_exact(a1 + bk1[k * H2 + n0 + 1]);
        hbuf[n0 + 2] = gelu_exact(a2 + bk1[k * H2 + n0 + 2]);
        hbuf[n0 + 3] = gelu_exact(a3 + bk1[k * H2 + n0 + 3]);
    }
    __syncthreads();

    // ---- Phase C: coarse (120) | Phase D: conf hidden (64) ----
    if (tid < TO) {
        const float* wk2 = Wk2 + k * H2 * TO;
        float a = bk2[k * TO + tid];
        for (int f = 0; f < H2; ++f)
            a = fmaf(hbuf[f], wk2[f * TO + tid], a);
        coarse[tid] = a;
    } else if (tid >= 128 && tid < 192) {
        int j = tid - 128;
        float a = 0.f;
        for (int f = 0; f < HH; ++f)
            a = fmaf(mf[f], Wf1[f * 64 + j], a);
        c1[j] = fmaxf(a + bf1[j], 0.f);
    }
    __syncthreads();
    if (tid == 0) {
        float a = bf2v[0];
        for (int j = 0; j < 64; ++j) a = fmaf(c1[j], Wf2[j], a);
        conf_out[b * KK + k] = a;
    }

    // ---- Phase E: traj=gelu(coarse@Wt+bt); rf = LN(traj+attn)*g+b (bf16) ----
    {
        const int cbase = ln * 8;
        F8 w0 = load8f(Wt + cbase);
        F8 w1 = load8f(Wt + HH + cbase);
        F8 b8 = load8f(bt + cbase);
        F8 g8 = load8f(lng + cbase);
        F8 bb8 = load8f(lnb + cbase);
        F8 a8 = load8b(attb + cbase);
        for (int r = 0; r < 15; ++r) {
            int t = w + 4 * r;
            float co0 = coarse[2 * t], co1 = coarse[2 * t + 1];
            float x[8]; float s = 0.f, s2 = 0.f;
#pragma unroll
            for (int j = 0; j < 8; ++j) {
                float vv = fmaf(co0, w0.v[j], fmaf(co1, w1.v[j], b8.v[j]));
                vv = gelu_exact(vv) + a8.v[j];
                x[j] = vv; s += vv; s2 = fmaf(vv, vv, s2);
            }
#pragma unroll
            for (int off = 32; off > 0; off >>= 1) {
                s += __shfl_xor(s, off);
                s2 += __shfl_xor(s2, off);
            }
            float mean = s * (1.0f / HH);
            float var = fmaf(-mean, mean, s2 * (1.0f / HH));
            float inv = rsqrtf(var + 1e-5f);
            unsigned int pk[4];
#pragma unroll
            for (int j = 0; j < 4; ++j) {
                float y0 = fmaf((x[2 * j] - mean) * inv, g8.v[2 * j], bb8.v[2 * j]);
                float y1 = fmaf((x[2 * j + 1] - mean) * inv, g8.v[2 * j + 1], bb8.v[2 * j + 1]);
                pk[j] = (unsigned int)f2bf(y0) | ((unsigned int)f2bf(y1) << 16);
            }
            *(uint4*)(rf + t * RFP + cbase) = make_uint4(pk[0], pk[1], pk[2], pk[3]);
        }
        *(uint4*)(rf + (60 + w) * RFP + cbase) = make_uint4(0, 0, 0, 0);
    }
    __syncthreads();

    // ---- Phase F: r=gelu(rf@Wr1+br1); offsets=r@Wr2 via MFMA ----
    {
        const unsigned short* wr1t_k = Wr1T + k * HH * HH;
        float po0[16], po1[16];
#pragma unroll
        for (int i = 0; i < 16; ++i) { po0[i] = 0.f; po1[i] = 0.f; }
        const int lane15 = ln & 15;
        const int quad = ln >> 4;
        const unsigned short* abase = rf + lane15 * RFP + quad * 8;

        for (int chunk = 0; chunk < 4; ++chunk) {
            const int n0 = chunk * 128 + w * 32;
            f32x4 acc[4][2];
#pragma unroll
            for (int rt = 0; rt < 4; ++rt) {
                f32x4 z = {0.f, 0.f, 0.f, 0.f};
                acc[rt][0] = z; acc[rt][1] = z;
            }
            const unsigned short* bp0 = wr1t_k + (n0 + lane15) * HH + quad * 8;
            const unsigned short* bp1 = bp0 + 16 * HH;
#pragma unroll 2
            for (int f0 = 0; f0 < HH; f0 += 32) {
                bf16x8 bfr0 = *(const bf16x8*)(bp0 + f0);
                bf16x8 bfr1 = *(const bf16x8*)(bp1 + f0);
#pragma unroll
                for (int rt = 0; rt < 4; ++rt) {
                    bf16x8 af = *(const bf16x8*)(abase + rt * 16 * RFP + f0);
                    acc[rt][0] = __builtin_amdgcn_mfma_f32_16x16x32_bf16(af, bfr0, acc[rt][0], 0, 0, 0);
                    acc[rt][1] = __builtin_amdgcn_mfma_f32_16x16x32_bf16(af, bfr1, acc[rt][1], 0, 0, 0);
                }
            }
#pragma unroll
            for (int nt = 0; nt < 2; ++nt) {
                const int col = n0 + nt * 16 + lane15;
                const float bb1 = br1[k * HH + col];
                const float w20 = Wr2[(k * HH + col) * 2];
                const float w21 = Wr2[(k * HH + col) * 2 + 1];
#pragma unroll
                for (int rt = 0; rt < 4; ++rt)
#pragma unroll
                    for (int i = 0; i < 4; ++i) {
                        float rv = gelu_exact(acc[rt][nt][i] + bb1);
                        po0[rt * 4 + i] = fmaf(rv, w20, po0[rt * 4 + i]);
                        po1[rt * 4 + i] = fmaf(rv, w21, po1[rt * 4 + i]);
                    }
            }
        }
#pragma unroll
        for (int off = 1; off < 16; off <<= 1) {
#pragma unroll
            for (int i = 0; i < 16; ++i) {
                po0[i] += __shfl_xor(po0[i], off);
                po1[i] += __shfl_xor(po1[i], off);
            }
        }
        if (lane15 == 0) {
#pragma unroll
            for (int i = 0; i < 16; ++i) {
                int row = (i / 4) * 16 + quad * 4 + (i % 4);
                atomicAdd(&po[row][0], po0[i]);
                atomicAdd(&po[row][1], po1[i]);
            }
        }
    }
    __syncthreads();

    // ---- predictions = coarse + offsets + br2 (fp32 out) ----
    if (tid < TO) {
        int t = tid >> 1, o = tid & 1;
        float v = coarse[tid] + po[t][o] + br2[k * 2 + o];
        pred_out[((b * KK + k) * TT + t) * 2 + o] = v;
    }
}

// ---------------- softmax over K for mode_probs (fp32 out) ----------------
__global__ void k_softmax(const float* __restrict__ conf, float* __restrict__ out) {
    int b = blockIdx.x * blockDim.x + threadIdx.x;
    if (b < BB) {
        float v[KK];
        float m = -1e30f;
        for (int i = 0; i < KK; ++i) { v[i] = conf[b * KK + i]; m = fmaxf(m, v[i]); }
        float s = 0.f;
        for (int i = 0; i < KK; ++i) { v[i] = expf(v[i] - m); s += v[i]; }
        float inv = 1.0f / s;
        for (int i = 0; i < KK; ++i) out[b * KK + i] = v[i] * inv;
    }
}

extern "C" void kernel_launch(void* const* d_in, const int* in_sizes, int n_in,
                              void* d_out, int out_size, void* d_ws, size_t ws_size,
                              hipStream_t stream) {
    // Inputs are fp32 (measured round 3: bf16-interpretation NaN'd, fp32 path finite).
    const float* I0  = (const float*)d_in[0];
    const float* I1  = (const float*)d_in[1];
    const float* I2  = (const float*)d_in[2];
    const float* MQ  = (const float*)d_in[3];
    const float* Wc1 = (const float*)d_in[4];
    const float* bc1 = (const float*)d_in[5];
    const float* Wc2 = (const float*)d_in[6];
    const float* bc2 = (const float*)d_in[7];
    const float* Wk1 = (const float*)d_in[8];
    const float* bk1 = (const float*)d_in[9];
    const float* Wk2 = (const float*)d_in[10];
    const float* bk2 = (const float*)d_in[11];
    const float* Wt  = (const float*)d_in[12];
    const float* bt  = (const float*)d_in[13];
    const float* Wv  = (const float*)d_in[18];
    const float* bv  = (const float*)d_in[19];
    const float* Wo  = (const float*)d_in[20];
    const float* bo  = (const float*)d_in[21];
    const float* lng = (const float*)d_in[22];
    const float* lnb = (const float*)d_in[23];
    const float* Wr1 = (const float*)d_in[24];
    const float* br1 = (const float*)d_in[25];
    const float* Wr2 = (const float*)d_in[26];
    const float* br2 = (const float*)d_in[27];
    const float* Wf1 = (const float*)d_in[28];
    const float* bf1 = (const float*)d_in[29];
    const float* Wf2 = (const float*)d_in[30];
    const float* bf2v = (const float*)d_in[31];

    // ws layout (~4.02 MB):
    //   regA [3 MB]: g1/vbuf (512 KB bf16 each, lifetimes disjoint) then Wr1T (3 MB bf16)
    //   ctx [512 KB bf16], attn [512 KB bf16], conf [12 KB fp32]
    unsigned short* regA = (unsigned short*)d_ws;
    unsigned short* g1v  = regA;
    unsigned short* wr1t = regA;
    unsigned short* ctx  = regA + KK * HH * HH;
    unsigned short* attn = ctx + BB * HH;
    float* conf = (float*)(attn + BB * HH);

    // Output is fp32 (reference returns float32; harness rule: bf16->bf16*, else float*).
    float* pred = (float*)d_out;
    float* probs = pred + BB * KK * TT * OO;

    k_gemm<1, true,  true ><<<dim3(8, 8), 256, 0, stream>>>(I0, I1, I2, Wc1, bc1, g1v, 3 * HH);
    k_gemm<0, false, false><<<dim3(8, 8), 256, 0, stream>>>(g1v, nullptr, nullptr, Wc2, bc2, ctx, HH);
    k_gemm<0, false, false><<<dim3(8, 8), 256, 0, stream>>>(ctx, nullptr, nullptr, Wv, bv, g1v, HH);
    k_gemm<0, false, false><<<dim3(8, 8), 256, 0, stream>>>(g1v, nullptr, nullptr, Wo, bo, attn, HH);
    k_transpose<<<dim3(16, 16, 6), 256, 0, stream>>>(Wr1, wr1t);
    k_fused<<<dim3(BB * KK), 256, 0, stream>>>(ctx, attn, MQ, Wk1, bk1, Wk2, bk2,
                                               Wt, bt, lng, lnb, wr1t, br1, Wr2, br2,
                                               Wf1, bf1, Wf2, bf2v, pred, conf);
    k_softmax<<<dim3(2), 256, 0, stream>>>(conf, probs);
}

// Round 5
// 794.637 us; speedup vs baseline: 1.4471x; 1.4471x over previous
//
#include <hip/hip_runtime.h>
#include <math.h>

#define BB 512
#define HH 512
#define KK 6
#define TT 60
#define OO 2
#define H2 1024
#define TO 120
#define RFP 520   // padded LDS row stride (bf16 elems)
#define HSP 1032  // padded h row stride (bf16 elems)

typedef __bf16 bf16x8 __attribute__((ext_vector_type(8)));
typedef float  f32x4  __attribute__((ext_vector_type(4)));

__device__ __forceinline__ float bf2f(unsigned short u) {
    union { unsigned int i; float f; } v; v.i = ((unsigned int)u) << 16; return v.f;
}
__device__ __forceinline__ unsigned short f2bf(float f) {
    union { float f; unsigned int i; } v; v.f = f;
    unsigned int b = v.i;
    return (unsigned short)((b + 0x7FFFu + ((b >> 16) & 1u)) >> 16); // RNE
}
__device__ __forceinline__ float gelu_exact(float x) {
    return 0.5f * x * (1.0f + erff(x * 0.70710678118654752f));
}

struct F8 { float v[8]; };
__device__ __forceinline__ F8 load8f(const float* p) {
    F8 r;
    float4 a = *(const float4*)p;
    float4 b = *(const float4*)(p + 4);
    r.v[0] = a.x; r.v[1] = a.y; r.v[2] = a.z; r.v[3] = a.w;
    r.v[4] = b.x; r.v[5] = b.y; r.v[6] = b.z; r.v[7] = b.w;
    return r;
}
__device__ __forceinline__ F8 load8b(const unsigned short* p) {
    ushort4 a = *(const ushort4*)p;
    ushort4 b = *(const ushort4*)(p + 4);
    F8 r;
    r.v[0] = bf2f(a.x); r.v[1] = bf2f(a.y); r.v[2] = bf2f(a.z); r.v[3] = bf2f(a.w);
    r.v[4] = bf2f(b.x); r.v[5] = bf2f(b.y); r.v[6] = bf2f(b.z); r.v[7] = bf2f(b.w);
    return r;
}

// ---------------- transpose Wr1 (K,H,H) fp32 -> Wr1T (K,H,H) bf16 [n][f] ----------------
__global__ void k_transpose(const float* __restrict__ in, unsigned short* __restrict__ out) {
    __shared__ unsigned short t[32][33];
    int k = blockIdx.z;
    int f0 = blockIdx.x * 32, n0 = blockIdx.y * 32;
    int r = threadIdx.x / 32, c = threadIdx.x % 32;
    const float* src = in + k * HH * HH;
    unsigned short* dst = out + k * HH * HH;
#pragma unroll
    for (int i = 0; i < 4; ++i)
        t[r + 8 * i][c] = f2bf(src[(f0 + r + 8 * i) * HH + n0 + c]);
    __syncthreads();
#pragma unroll
    for (int i = 0; i < 4; ++i)
        dst[(n0 + r + 8 * i) * HH + f0 + c] = t[c][r + 8 * i];
}

// --------- ctx-chain GEMM: C(512x512 bf16) = [gelu](A @ B + bias) ---------
template <int ADT, bool CONCAT, bool GELU>
__launch_bounds__(256)
__global__ void k_gemm(const void* __restrict__ A0, const void* __restrict__ A1,
                       const void* __restrict__ A2, const float* __restrict__ Bm,
                       const float* __restrict__ bias, unsigned short* __restrict__ C,
                       int Kd) {
    __shared__ float As[64][17];
    __shared__ float Bs[16][65];
    int tid = threadIdx.x;
    int tx = tid % 16, ty = tid / 16;
    int bm = blockIdx.x * 64, bn = blockIdx.y * 64;
    float acc[4][4] = {};
    for (int k0 = 0; k0 < Kd; k0 += 16) {
        {
            int r = tid / 4, cc = (tid % 4) * 4;
            int c = k0 + cc;
            float a4[4];
            if (CONCAT) {
                const float* src = (c < HH) ? (const float*)A0 : (c < 2 * HH) ? (const float*)A1 : (const float*)A2;
                int cm = (c < HH) ? c : (c < 2 * HH) ? (c - HH) : (c - 2 * HH);
                float4 v = *(const float4*)(src + (bm + r) * HH + cm);
                a4[0] = v.x; a4[1] = v.y; a4[2] = v.z; a4[3] = v.w;
            } else if (ADT == 1) {
                float4 v = *(const float4*)((const float*)A0 + (bm + r) * Kd + c);
                a4[0] = v.x; a4[1] = v.y; a4[2] = v.z; a4[3] = v.w;
            } else {
                ushort4 v = *(const ushort4*)((const unsigned short*)A0 + (bm + r) * Kd + c);
                a4[0] = bf2f(v.x); a4[1] = bf2f(v.y); a4[2] = bf2f(v.z); a4[3] = bf2f(v.w);
            }
            As[r][cc] = a4[0]; As[r][cc + 1] = a4[1]; As[r][cc + 2] = a4[2]; As[r][cc + 3] = a4[3];
        }
        {
            int r = tid / 16, cc = (tid % 16) * 4;
            float4 v = *(const float4*)(Bm + (k0 + r) * HH + bn + cc);
            Bs[r][cc] = v.x; Bs[r][cc + 1] = v.y; Bs[r][cc + 2] = v.z; Bs[r][cc + 3] = v.w;
        }
        __syncthreads();
#pragma unroll
        for (int kk = 0; kk < 16; ++kk) {
            float a[4], bv[4];
#pragma unroll
            for (int i = 0; i < 4; ++i) a[i] = As[ty * 4 + i][kk];
#pragma unroll
            for (int j = 0; j < 4; ++j) bv[j] = Bs[kk][tx * 4 + j];
#pragma unroll
            for (int i = 0; i < 4; ++i)
#pragma unroll
                for (int j = 0; j < 4; ++j)
                    acc[i][j] = fmaf(a[i], bv[j], acc[i][j]);
        }
        __syncthreads();
    }
#pragma unroll
    for (int i = 0; i < 4; ++i) {
        int row = bm + ty * 4 + i;
#pragma unroll
        for (int j = 0; j < 4; ++j) {
            int col = bn + tx * 4 + j;
            float v = acc[i][j] + bias[col];
            if (GELU) v = gelu_exact(v);
            C[row * HH + col] = f2bf(v);
        }
    }
}

// ---------------- k_bc: batched coarse-heads + conf, per (k, 32 b-rows) ----------------
// MFMA everywhere. A-fragment: [m=lane15][k=quad*8+j]; B-fragment: [n=lane15][k=quad*8+j];
// C/D: col=lane15, row=quad*4+reg (verified by round-4 Phase F passing).
__launch_bounds__(256)
__global__ void k_bc(const unsigned short* __restrict__ ctx, const float* __restrict__ mq,
                     const float* __restrict__ Wk1, const float* __restrict__ bk1,
                     const float* __restrict__ Wk2, const float* __restrict__ bk2,
                     const float* __restrict__ Wf1, const float* __restrict__ bf1,
                     const float* __restrict__ Wf2, const float* __restrict__ bf2v,
                     unsigned short* __restrict__ coarse_out, float* __restrict__ conf_out)
{
    __shared__ __align__(16) unsigned short mf[32 * RFP];   // 33,280 B
    __shared__ __align__(16) unsigned short hs[32 * HSP];   // 66,048 B

    const int tid = threadIdx.x;
    const int k = blockIdx.x % KK;
    const int b0 = (blockIdx.x / KK) * 32;
    const int w = tid >> 6;
    const int ln = tid & 63;
    const int lane15 = ln & 15;
    const int quad = ln >> 4;

    // ---- stage mf = bf16(ctx + mq[k]) rows b0..b0+31 ----
    {
        int r = tid >> 3;            // 32 rows, 8 threads/row
        int c0 = (tid & 7) * 64;
        const unsigned short* cp = ctx + (b0 + r) * HH + c0;
        const float* qp = mq + k * HH + c0;
        unsigned short* dp = mf + r * RFP + c0;
        for (int c = 0; c < 64; c += 8) {
            F8 cv = load8b(cp + c);
            F8 qv = load8f(qp + c);
            unsigned int pk[4];
#pragma unroll
            for (int j = 0; j < 4; ++j)
                pk[j] = (unsigned int)f2bf(cv.v[2 * j] + qv.v[2 * j]) |
                        ((unsigned int)f2bf(cv.v[2 * j + 1] + qv.v[2 * j + 1]) << 16);
            *(uint4*)(dp + c) = make_uint4(pk[0], pk[1], pk[2], pk[3]);
        }
    }
    __syncthreads();

    // ---- GEMM1: h = gelu(mf @ Wk1[k] + bk1[k]) -> hs (bf16). Wave n-slice = 256. ----
    {
        const float* wk1 = Wk1 + k * HH * H2;
        const float* bk1p = bk1 + k * H2;
        for (int g = 0; g < 4; ++g) {            // 4 groups of 4 n-tiles
            f32x4 acc[2][4];
#pragma unroll
            for (int mt = 0; mt < 2; ++mt)
#pragma unroll
                for (int nt = 0; nt < 4; ++nt) { f32x4 z = {0.f,0.f,0.f,0.f}; acc[mt][nt] = z; }
            for (int f0 = 0; f0 < HH; f0 += 32) {
                bf16x8 a0 = *(const bf16x8*)(mf + lane15 * RFP + f0 + quad * 8);
                bf16x8 a1 = *(const bf16x8*)(mf + (16 + lane15) * RFP + f0 + quad * 8);
#pragma unroll
                for (int nt = 0; nt < 4; ++nt) {
                    const int n = w * 256 + g * 64 + nt * 16 + lane15;
                    const float* bp = wk1 + (f0 + quad * 8) * H2 + n;
                    bf16x8 bf;
#pragma unroll
                    for (int j = 0; j < 8; ++j) bf[j] = (__bf16)bp[j * H2];
                    acc[0][nt] = __builtin_amdgcn_mfma_f32_16x16x32_bf16(a0, bf, acc[0][nt], 0, 0, 0);
                    acc[1][nt] = __builtin_amdgcn_mfma_f32_16x16x32_bf16(a1, bf, acc[1][nt], 0, 0, 0);
                }
            }
#pragma unroll
            for (int nt = 0; nt < 4; ++nt) {
                const int n = w * 256 + g * 64 + nt * 16 + lane15;
                const float bias = bk1p[n];
#pragma unroll
                for (int mt = 0; mt < 2; ++mt)
#pragma unroll
                    for (int reg = 0; reg < 4; ++reg) {
                        int row = mt * 16 + quad * 4 + reg;
                        hs[row * HSP + n] = f2bf(gelu_exact(acc[mt][nt][reg] + bias));
                    }
            }
        }
    }
    __syncthreads();

    // ---- GEMM2: coarse = h @ Wk2[k] + bk2[k]. Wave n-slice = 32 (pad to 128). ----
    {
        const float* wk2 = Wk2 + k * H2 * TO;
        f32x4 acc[2][2];
#pragma unroll
        for (int mt = 0; mt < 2; ++mt)
#pragma unroll
            for (int nt = 0; nt < 2; ++nt) { f32x4 z = {0.f,0.f,0.f,0.f}; acc[mt][nt] = z; }
        for (int f0 = 0; f0 < H2; f0 += 32) {
            bf16x8 a0 = *(const bf16x8*)(hs + lane15 * HSP + f0 + quad * 8);
            bf16x8 a1 = *(const bf16x8*)(hs + (16 + lane15) * HSP + f0 + quad * 8);
#pragma unroll
            for (int nt = 0; nt < 2; ++nt) {
                const int n = w * 32 + nt * 16 + lane15;
                bf16x8 bf;
#pragma unroll
                for (int j = 0; j < 8; ++j)
                    bf[j] = (n < TO) ? (__bf16)wk2[(f0 + quad * 8 + j) * TO + n] : (__bf16)0.f;
                acc[0][nt] = __builtin_amdgcn_mfma_f32_16x16x32_bf16(a0, bf, acc[0][nt], 0, 0, 0);
                acc[1][nt] = __builtin_amdgcn_mfma_f32_16x16x32_bf16(a1, bf, acc[1][nt], 0, 0, 0);
            }
        }
#pragma unroll
        for (int nt = 0; nt < 2; ++nt) {
            const int n = w * 32 + nt * 16 + lane15;
            if (n < TO) {
                const float bias = bk2[k * TO + n];
#pragma unroll
                for (int mt = 0; mt < 2; ++mt)
#pragma unroll
                    for (int reg = 0; reg < 4; ++reg) {
                        int row = mt * 16 + quad * 4 + reg;
                        coarse_out[((b0 + row) * KK + k) * TO + n] = f2bf(acc[mt][nt][reg] + bias);
                    }
            }
        }
    }

    // ---- GEMM3 (wave 0 only): conf = relu(mf @ Wf1 + bf1) @ Wf2 + bf2 ----
    if (w == 0) {
        f32x4 acc[2][4];
#pragma unroll
        for (int mt = 0; mt < 2; ++mt)
#pragma unroll
            for (int nt = 0; nt < 4; ++nt) { f32x4 z = {0.f,0.f,0.f,0.f}; acc[mt][nt] = z; }
        for (int f0 = 0; f0 < HH; f0 += 32) {
            bf16x8 a0 = *(const bf16x8*)(mf + lane15 * RFP + f0 + quad * 8);
            bf16x8 a1 = *(const bf16x8*)(mf + (16 + lane15) * RFP + f0 + quad * 8);
#pragma unroll
            for (int nt = 0; nt < 4; ++nt) {
                const int n = nt * 16 + lane15;
                const float* bp = Wf1 + (f0 + quad * 8) * 64 + n;
                bf16x8 bf;
#pragma unroll
                for (int j = 0; j < 8; ++j) bf[j] = (__bf16)bp[j * 64];
                acc[0][nt] = __builtin_amdgcn_mfma_f32_16x16x32_bf16(a0, bf, acc[0][nt], 0, 0, 0);
                acc[1][nt] = __builtin_amdgcn_mfma_f32_16x16x32_bf16(a1, bf, acc[1][nt], 0, 0, 0);
            }
        }
        const float b2 = bf2v[0];
#pragma unroll
        for (int mt = 0; mt < 2; ++mt)
#pragma unroll
            for (int reg = 0; reg < 4; ++reg) {
                float s = 0.f;
#pragma unroll
                for (int nt = 0; nt < 4; ++nt) {
                    const int n = nt * 16 + lane15;
                    s = fmaf(fmaxf(acc[mt][nt][reg] + bf1[n], 0.f), Wf2[n], s);
                }
#pragma unroll
                for (int off = 1; off < 16; off <<= 1) s += __shfl_xor(s, off);
                if (lane15 == 0) {
                    int row = mt * 16 + quad * 4 + reg;
                    conf_out[(b0 + row) * KK + k] = s + b2;
                }
            }
    }
}

// ---------------- k_ef: per (b,k) traj+LN (Phase E) + refine MFMA (Phase F) ----------------
__launch_bounds__(256, 2)
__global__ void k_ef(
    const unsigned short* __restrict__ attn, const unsigned short* __restrict__ coarse_ws,
    const float* __restrict__ Wt,  const float* __restrict__ bt,
    const float* __restrict__ lng, const float* __restrict__ lnb,
    const unsigned short* __restrict__ Wr1T, const float* __restrict__ br1,
    const float* __restrict__ Wr2, const float* __restrict__ br2,
    float* __restrict__ pred_out)
{
    __shared__ __align__(16) unsigned short rf[64 * RFP];
    __shared__ float coarse[TO];
    __shared__ float po[64][2];

    const int tid = threadIdx.x;
    const int b = blockIdx.x / KK;
    const int k = blockIdx.x % KK;
    const int w = tid >> 6;
    const int ln = tid & 63;

    const unsigned short* attb = attn + b * HH;

    if (tid < TO) coarse[tid] = bf2f(coarse_ws[(b * KK + k) * TO + tid]);
    if (tid >= 128 && tid < 256) ((float*)po)[tid - 128] = 0.f;
    __syncthreads();

    // ---- Phase E: traj=gelu(coarse@Wt+bt); rf = LN(traj+attn)*g+b (bf16) ----
    {
        const int cbase = ln * 8;
        F8 w0 = load8f(Wt + cbase);
        F8 w1 = load8f(Wt + HH + cbase);
        F8 b8 = load8f(bt + cbase);
        F8 g8 = load8f(lng + cbase);
        F8 bb8 = load8f(lnb + cbase);
        F8 a8 = load8b(attb + cbase);
        for (int r = 0; r < 15; ++r) {
            int t = w + 4 * r;
            float co0 = coarse[2 * t], co1 = coarse[2 * t + 1];
            float x[8]; float s = 0.f, s2 = 0.f;
#pragma unroll
            for (int j = 0; j < 8; ++j) {
                float vv = fmaf(co0, w0.v[j], fmaf(co1, w1.v[j], b8.v[j]));
                vv = gelu_exact(vv) + a8.v[j];
                x[j] = vv; s += vv; s2 = fmaf(vv, vv, s2);
            }
#pragma unroll
            for (int off = 32; off > 0; off >>= 1) {
                s += __shfl_xor(s, off);
                s2 += __shfl_xor(s2, off);
            }
            float mean = s * (1.0f / HH);
            float var = fmaf(-mean, mean, s2 * (1.0f / HH));
            float inv = rsqrtf(var + 1e-5f);
            unsigned int pk[4];
#pragma unroll
            for (int j = 0; j < 4; ++j) {
                float y0 = fmaf((x[2 * j] - mean) * inv, g8.v[2 * j], bb8.v[2 * j]);
                float y1 = fmaf((x[2 * j + 1] - mean) * inv, g8.v[2 * j + 1], bb8.v[2 * j + 1]);
                pk[j] = (unsigned int)f2bf(y0) | ((unsigned int)f2bf(y1) << 16);
            }
            *(uint4*)(rf + t * RFP + cbase) = make_uint4(pk[0], pk[1], pk[2], pk[3]);
        }
        *(uint4*)(rf + (60 + w) * RFP + cbase) = make_uint4(0, 0, 0, 0);
    }
    __syncthreads();

    // ---- Phase F: r=gelu(rf@Wr1+br1); offsets=r@Wr2 via MFMA ----
    {
        const unsigned short* wr1t_k = Wr1T + k * HH * HH;
        float po0[16], po1[16];
#pragma unroll
        for (int i = 0; i < 16; ++i) { po0[i] = 0.f; po1[i] = 0.f; }
        const int lane15 = ln & 15;
        const int quad = ln >> 4;
        const unsigned short* abase = rf + lane15 * RFP + quad * 8;

        for (int chunk = 0; chunk < 4; ++chunk) {
            const int n0 = chunk * 128 + w * 32;
            f32x4 acc[4][2];
#pragma unroll
            for (int rt = 0; rt < 4; ++rt) {
                f32x4 z = {0.f, 0.f, 0.f, 0.f};
                acc[rt][0] = z; acc[rt][1] = z;
            }
            const unsigned short* bp0 = wr1t_k + (n0 + lane15) * HH + quad * 8;
            const unsigned short* bp1 = bp0 + 16 * HH;
#pragma unroll 2
            for (int f0 = 0; f0 < HH; f0 += 32) {
                bf16x8 bfr0 = *(const bf16x8*)(bp0 + f0);
                bf16x8 bfr1 = *(const bf16x8*)(bp1 + f0);
#pragma unroll
                for (int rt = 0; rt < 4; ++rt) {
                    bf16x8 af = *(const bf16x8*)(abase + rt * 16 * RFP + f0);
                    acc[rt][0] = __builtin_amdgcn_mfma_f32_16x16x32_bf16(af, bfr0, acc[rt][0], 0, 0, 0);
                    acc[rt][1] = __builtin_amdgcn_mfma_f32_16x16x32_bf16(af, bfr1, acc[rt][1], 0, 0, 0);
                }
            }
#pragma unroll
            for (int nt = 0; nt < 2; ++nt) {
                const int col = n0 + nt * 16 + lane15;
                const float bb1 = br1[k * HH + col];
                const float w20 = Wr2[(k * HH + col) * 2];
                const float w21 = Wr2[(k * HH + col) * 2 + 1];
#pragma unroll
                for (int rt = 0; rt < 4; ++rt)
#pragma unroll
                    for (int i = 0; i < 4; ++i) {
                        float rv = gelu_exact(acc[rt][nt][i] + bb1);
                        po0[rt * 4 + i] = fmaf(rv, w20, po0[rt * 4 + i]);
                        po1[rt * 4 + i] = fmaf(rv, w21, po1[rt * 4 + i]);
                    }
            }
        }
#pragma unroll
        for (int off = 1; off < 16; off <<= 1) {
#pragma unroll
            for (int i = 0; i < 16; ++i) {
                po0[i] += __shfl_xor(po0[i], off);
                po1[i] += __shfl_xor(po1[i], off);
            }
        }
        if ((ln & 15) == 0) {
            const int quad2 = ln >> 4;
#pragma unroll
            for (int i = 0; i < 16; ++i) {
                int row = (i / 4) * 16 + quad2 * 4 + (i % 4);
                atomicAdd(&po[row][0], po0[i]);
                atomicAdd(&po[row][1], po1[i]);
            }
        }
    }
    __syncthreads();

    // ---- predictions = coarse + offsets + br2 (fp32 out) ----
    if (tid < TO) {
        int t = tid >> 1, o = tid & 1;
        float v = coarse[tid] + po[t][o] + br2[k * 2 + o];
        pred_out[((b * KK + k) * TT + t) * 2 + o] = v;
    }
}

// ---------------- softmax over K for mode_probs (fp32 out) ----------------
__global__ void k_softmax(const float* __restrict__ conf, float* __restrict__ out) {
    int b = blockIdx.x * blockDim.x + threadIdx.x;
    if (b < BB) {
        float v[KK];
        float m = -1e30f;
        for (int i = 0; i < KK; ++i) { v[i] = conf[b * KK + i]; m = fmaxf(m, v[i]); }
        float s = 0.f;
        for (int i = 0; i < KK; ++i) { v[i] = expf(v[i] - m); s += v[i]; }
        float inv = 1.0f / s;
        for (int i = 0; i < KK; ++i) out[b * KK + i] = v[i] * inv;
    }
}

extern "C" void kernel_launch(void* const* d_in, const int* in_sizes, int n_in,
                              void* d_out, int out_size, void* d_ws, size_t ws_size,
                              hipStream_t stream) {
    const float* I0  = (const float*)d_in[0];
    const float* I1  = (const float*)d_in[1];
    const float* I2  = (const float*)d_in[2];
    const float* MQ  = (const float*)d_in[3];
    const float* Wc1 = (const float*)d_in[4];
    const float* bc1 = (const float*)d_in[5];
    const float* Wc2 = (const float*)d_in[6];
    const float* bc2 = (const float*)d_in[7];
    const float* Wk1 = (const float*)d_in[8];
    const float* bk1 = (const float*)d_in[9];
    const float* Wk2 = (const float*)d_in[10];
    const float* bk2 = (const float*)d_in[11];
    const float* Wt  = (const float*)d_in[12];
    const float* bt  = (const float*)d_in[13];
    const float* Wv  = (const float*)d_in[18];
    const float* bv  = (const float*)d_in[19];
    const float* Wo  = (const float*)d_in[20];
    const float* bo  = (const float*)d_in[21];
    const float* lng = (const float*)d_in[22];
    const float* lnb = (const float*)d_in[23];
    const float* Wr1 = (const float*)d_in[24];
    const float* br1 = (const float*)d_in[25];
    const float* Wr2 = (const float*)d_in[26];
    const float* br2 = (const float*)d_in[27];
    const float* Wf1 = (const float*)d_in[28];
    const float* bf1 = (const float*)d_in[29];
    const float* Wf2 = (const float*)d_in[30];
    const float* bf2v = (const float*)d_in[31];

    // ws layout (4.94 MB), ushort units:
    //   wr1t   [0 .. 1,572,864)         3 MB bf16; first 512 KB doubles as g1/vbuf tmp
    //   ctx    [1,572,864 .. +262,144)  bf16
    //   attn   [1,835,008 .. +262,144)  bf16
    //   coarse [2,097,152 .. +368,640)  bf16 (B,K,120)
    //   conf   byte 4,931,584 .. +12,288 fp32
    unsigned short* wsu   = (unsigned short*)d_ws;
    unsigned short* wr1t  = wsu;
    unsigned short* tmp   = wsu;                       // g1/vbuf alias (dead before transpose)
    unsigned short* ctx   = wsu + 1572864;
    unsigned short* attn  = wsu + 1835008;
    unsigned short* coarse= wsu + 2097152;
    float* conf = (float*)(wsu + 2465792);

    float* pred = (float*)d_out;
    float* probs = pred + BB * KK * TT * OO;

    k_gemm<1, true,  true ><<<dim3(8, 8), 256, 0, stream>>>(I0, I1, I2, Wc1, bc1, tmp, 3 * HH);
    k_gemm<0, false, false><<<dim3(8, 8), 256, 0, stream>>>(tmp, nullptr, nullptr, Wc2, bc2, ctx, HH);
    k_gemm<0, false, false><<<dim3(8, 8), 256, 0, stream>>>(ctx, nullptr, nullptr, Wv, bv, tmp, HH);
    k_gemm<0, false, false><<<dim3(8, 8), 256, 0, stream>>>(tmp, nullptr, nullptr, Wo, bo, attn, HH);
    k_transpose<<<dim3(16, 16, 6), 256, 0, stream>>>(Wr1, wr1t);   // after tmp is dead
    k_bc<<<dim3(96), 256, 0, stream>>>(ctx, MQ, Wk1, bk1, Wk2, bk2, Wf1, bf1, Wf2, bf2v,
                                       coarse, conf);
    k_ef<<<dim3(BB * KK), 256, 0, stream>>>(attn, coarse, Wt, bt, lng, lnb,
                                            wr1t, br1, Wr2, br2, pred);
    k_softmax<<<dim3(2), 256, 0, stream>>>(conf, probs);
}

// Round 6
// 591.110 us; speedup vs baseline: 1.9453x; 1.3443x over previous
//
#include <hip/hip_runtime.h>
#include <math.h>

#define BB 512
#define HH 512
#define KK 6
#define TT 60
#define OO 2
#define H2 1024
#define TO 120
#define RFP 520   // padded LDS row stride (bf16 elems)
#define HSP 1032  // padded h row stride (bf16 elems)

typedef __bf16 bf16x8 __attribute__((ext_vector_type(8)));
typedef float  f32x4  __attribute__((ext_vector_type(4)));

__device__ __forceinline__ float bf2f(unsigned short u) {
    union { unsigned int i; float f; } v; v.i = ((unsigned int)u) << 16; return v.f;
}
__device__ __forceinline__ unsigned short f2bf(float f) {
    union { float f; unsigned int i; } v; v.f = f;
    unsigned int b = v.i;
    return (unsigned short)((b + 0x7FFFu + ((b >> 16) & 1u)) >> 16); // RNE
}
__device__ __forceinline__ float gelu_exact(float x) {
    return 0.5f * x * (1.0f + erff(x * 0.70710678118654752f));
}
// tanh-approx GELU via sigmoid (max abs err ~3e-4 vs exact erf; used only where
// error budget allows: traj pre-LN and refine hidden r).
__device__ __forceinline__ float gelu_fast(float x) {
    float x3 = x * x * x;
    float z = fmaf(0.0713548162726f, x3, 1.5957691216057308f * x);
    return x / (1.0f + __expf(-z));
}

struct F8 { float v[8]; };
__device__ __forceinline__ F8 load8f(const float* p) {
    F8 r;
    float4 a = *(const float4*)p;
    float4 b = *(const float4*)(p + 4);
    r.v[0] = a.x; r.v[1] = a.y; r.v[2] = a.z; r.v[3] = a.w;
    r.v[4] = b.x; r.v[5] = b.y; r.v[6] = b.z; r.v[7] = b.w;
    return r;
}
__device__ __forceinline__ F8 load8b(const unsigned short* p) {
    ushort4 a = *(const ushort4*)p;
    ushort4 b = *(const ushort4*)(p + 4);
    F8 r;
    r.v[0] = bf2f(a.x); r.v[1] = bf2f(a.y); r.v[2] = bf2f(a.z); r.v[3] = bf2f(a.w);
    r.v[4] = bf2f(b.x); r.v[5] = bf2f(b.y); r.v[6] = bf2f(b.z); r.v[7] = bf2f(b.w);
    return r;
}

// ---------------- transpose Wr1 (K,H,H) fp32 -> Wr1T (K,H,H) bf16 [n][f] ----------------
__global__ void k_transpose(const float* __restrict__ in, unsigned short* __restrict__ out) {
    __shared__ unsigned short t[32][33];
    int k = blockIdx.z;
    int f0 = blockIdx.x * 32, n0 = blockIdx.y * 32;
    int r = threadIdx.x / 32, c = threadIdx.x % 32;
    const float* src = in + k * HH * HH;
    unsigned short* dst = out + k * HH * HH;
#pragma unroll
    for (int i = 0; i < 4; ++i)
        t[r + 8 * i][c] = f2bf(src[(f0 + r + 8 * i) * HH + n0 + c]);
    __syncthreads();
#pragma unroll
    for (int i = 0; i < 4; ++i)
        dst[(n0 + r + 8 * i) * HH + f0 + c] = t[c][r + 8 * i];
}

// --------- MFMA ctx-chain GEMM: C(512x512 bf16) = [gelu](A @ B + bias) ---------
// Tile 32(M)x64(N), 4 waves (16 cols each), K chunked by 512.
// CONCAT: chunk kc reads fp32 A{0,1,2}; else single bf16 A0 chunk.
// Fragments (verified by k_bc round 5): A[m=lane15][k=quad*8+j], B[n=lane15][k=quad*8+j],
// C/D col=lane15,row=quad*4+reg.
template <bool CONCAT, bool GELU>
__launch_bounds__(256)
__global__ void k_gemm_m(const void* __restrict__ A0, const void* __restrict__ A1,
                         const void* __restrict__ A2, const float* __restrict__ Bm,
                         const float* __restrict__ bias, unsigned short* __restrict__ C,
                         int nchunks) {
    __shared__ __align__(16) unsigned short As[32 * RFP];  // 33,280 B
    const int tid = threadIdx.x;
    const int bm = blockIdx.x * 32;
    const int bn = blockIdx.y * 64;
    const int w = tid >> 6, ln = tid & 63;
    const int lane15 = ln & 15, quad = ln >> 4;
    const int n = bn + w * 16 + lane15;

    f32x4 acc0 = {0.f, 0.f, 0.f, 0.f}, acc1 = {0.f, 0.f, 0.f, 0.f};

    for (int kc = 0; kc < nchunks; ++kc) {
        {   // stage A rows bm..bm+31, cols [kc*512, kc*512+512) -> bf16 LDS
            int r = tid >> 3, c0 = (tid & 7) * 64;
            unsigned short* dp = As + r * RFP + c0;
            if (CONCAT) {
                const float* src = (kc == 0) ? (const float*)A0
                                 : (kc == 1) ? (const float*)A1 : (const float*)A2;
                const float* sp = src + (bm + r) * HH + c0;
                for (int c = 0; c < 64; c += 8) {
                    F8 v = load8f(sp + c);
                    unsigned int pk[4];
#pragma unroll
                    for (int j = 0; j < 4; ++j)
                        pk[j] = (unsigned int)f2bf(v.v[2 * j]) |
                                ((unsigned int)f2bf(v.v[2 * j + 1]) << 16);
                    *(uint4*)(dp + c) = make_uint4(pk[0], pk[1], pk[2], pk[3]);
                }
            } else {
                const unsigned short* sp = (const unsigned short*)A0 + (bm + r) * HH + c0;
                for (int c = 0; c < 64; c += 8)
                    *(uint4*)(dp + c) = *(const uint4*)(sp + c);
            }
        }
        __syncthreads();
        for (int f0 = 0; f0 < HH; f0 += 32) {
            bf16x8 a0 = *(const bf16x8*)(As + lane15 * RFP + f0 + quad * 8);
            bf16x8 a1 = *(const bf16x8*)(As + (16 + lane15) * RFP + f0 + quad * 8);
            const float* bp = Bm + (kc * HH + f0 + quad * 8) * HH + n;
            bf16x8 bf;
#pragma unroll
            for (int j = 0; j < 8; ++j) bf[j] = (__bf16)bp[j * HH];
            acc0 = __builtin_amdgcn_mfma_f32_16x16x32_bf16(a0, bf, acc0, 0, 0, 0);
            acc1 = __builtin_amdgcn_mfma_f32_16x16x32_bf16(a1, bf, acc1, 0, 0, 0);
        }
        __syncthreads();
    }
    const float bb = bias[n];
#pragma unroll
    for (int reg = 0; reg < 4; ++reg) {
        float v0 = acc0[reg] + bb, v1 = acc1[reg] + bb;
        if (GELU) { v0 = gelu_exact(v0); v1 = gelu_exact(v1); }
        C[(bm + quad * 4 + reg) * HH + n] = f2bf(v0);
        C[(bm + 16 + quad * 4 + reg) * HH + n] = f2bf(v1);
    }
}

// ---------------- k_bc: batched coarse-heads + conf, per (k, 32 b-rows) ----------------
__launch_bounds__(256)
__global__ void k_bc(const unsigned short* __restrict__ ctx, const float* __restrict__ mq,
                     const float* __restrict__ Wk1, const float* __restrict__ bk1,
                     const float* __restrict__ Wk2, const float* __restrict__ bk2,
                     const float* __restrict__ Wf1, const float* __restrict__ bf1,
                     const float* __restrict__ Wf2, const float* __restrict__ bf2v,
                     unsigned short* __restrict__ coarse_out, float* __restrict__ conf_out)
{
    __shared__ __align__(16) unsigned short mf[32 * RFP];   // 33,280 B
    __shared__ __align__(16) unsigned short hs[32 * HSP];   // 66,048 B

    const int tid = threadIdx.x;
    const int k = blockIdx.x % KK;
    const int b0 = (blockIdx.x / KK) * 32;
    const int w = tid >> 6;
    const int ln = tid & 63;
    const int lane15 = ln & 15;
    const int quad = ln >> 4;

    // ---- stage mf = bf16(ctx + mq[k]) rows b0..b0+31 ----
    {
        int r = tid >> 3;
        int c0 = (tid & 7) * 64;
        const unsigned short* cp = ctx + (b0 + r) * HH + c0;
        const float* qp = mq + k * HH + c0;
        unsigned short* dp = mf + r * RFP + c0;
        for (int c = 0; c < 64; c += 8) {
            F8 cv = load8b(cp + c);
            F8 qv = load8f(qp + c);
            unsigned int pk[4];
#pragma unroll
            for (int j = 0; j < 4; ++j)
                pk[j] = (unsigned int)f2bf(cv.v[2 * j] + qv.v[2 * j]) |
                        ((unsigned int)f2bf(cv.v[2 * j + 1] + qv.v[2 * j + 1]) << 16);
            *(uint4*)(dp + c) = make_uint4(pk[0], pk[1], pk[2], pk[3]);
        }
    }
    __syncthreads();

    // ---- GEMM1: h = gelu(mf @ Wk1[k] + bk1[k]) -> hs (bf16) ----
    {
        const float* wk1 = Wk1 + k * HH * H2;
        const float* bk1p = bk1 + k * H2;
        for (int g = 0; g < 4; ++g) {
            f32x4 acc[2][4];
#pragma unroll
            for (int mt = 0; mt < 2; ++mt)
#pragma unroll
                for (int nt = 0; nt < 4; ++nt) { f32x4 z = {0.f,0.f,0.f,0.f}; acc[mt][nt] = z; }
            for (int f0 = 0; f0 < HH; f0 += 32) {
                bf16x8 a0 = *(const bf16x8*)(mf + lane15 * RFP + f0 + quad * 8);
                bf16x8 a1 = *(const bf16x8*)(mf + (16 + lane15) * RFP + f0 + quad * 8);
#pragma unroll
                for (int nt = 0; nt < 4; ++nt) {
                    const int n = w * 256 + g * 64 + nt * 16 + lane15;
                    const float* bp = wk1 + (f0 + quad * 8) * H2 + n;
                    bf16x8 bf;
#pragma unroll
                    for (int j = 0; j < 8; ++j) bf[j] = (__bf16)bp[j * H2];
                    acc[0][nt] = __builtin_amdgcn_mfma_f32_16x16x32_bf16(a0, bf, acc[0][nt], 0, 0, 0);
                    acc[1][nt] = __builtin_amdgcn_mfma_f32_16x16x32_bf16(a1, bf, acc[1][nt], 0, 0, 0);
                }
            }
#pragma unroll
            for (int nt = 0; nt < 4; ++nt) {
                const int n = w * 256 + g * 64 + nt * 16 + lane15;
                const float bias = bk1p[n];
#pragma unroll
                for (int mt = 0; mt < 2; ++mt)
#pragma unroll
                    for (int reg = 0; reg < 4; ++reg) {
                        int row = mt * 16 + quad * 4 + reg;
                        hs[row * HSP + n] = f2bf(gelu_exact(acc[mt][nt][reg] + bias));
                    }
            }
        }
    }
    __syncthreads();

    // ---- GEMM2: coarse = h @ Wk2[k] + bk2[k] ----
    {
        const float* wk2 = Wk2 + k * H2 * TO;
        f32x4 acc[2][2];
#pragma unroll
        for (int mt = 0; mt < 2; ++mt)
#pragma unroll
            for (int nt = 0; nt < 2; ++nt) { f32x4 z = {0.f,0.f,0.f,0.f}; acc[mt][nt] = z; }
        for (int f0 = 0; f0 < H2; f0 += 32) {
            bf16x8 a0 = *(const bf16x8*)(hs + lane15 * HSP + f0 + quad * 8);
            bf16x8 a1 = *(const bf16x8*)(hs + (16 + lane15) * HSP + f0 + quad * 8);
#pragma unroll
            for (int nt = 0; nt < 2; ++nt) {
                const int n = w * 32 + nt * 16 + lane15;
                bf16x8 bf;
#pragma unroll
                for (int j = 0; j < 8; ++j)
                    bf[j] = (n < TO) ? (__bf16)wk2[(f0 + quad * 8 + j) * TO + n] : (__bf16)0.f;
                acc[0][nt] = __builtin_amdgcn_mfma_f32_16x16x32_bf16(a0, bf, acc[0][nt], 0, 0, 0);
                acc[1][nt] = __builtin_amdgcn_mfma_f32_16x16x32_bf16(a1, bf, acc[1][nt], 0, 0, 0);
            }
        }
#pragma unroll
        for (int nt = 0; nt < 2; ++nt) {
            const int n = w * 32 + nt * 16 + lane15;
            if (n < TO) {
                const float bias = bk2[k * TO + n];
#pragma unroll
                for (int mt = 0; mt < 2; ++mt)
#pragma unroll
                    for (int reg = 0; reg < 4; ++reg) {
                        int row = mt * 16 + quad * 4 + reg;
                        coarse_out[((b0 + row) * KK + k) * TO + n] = f2bf(acc[mt][nt][reg] + bias);
                    }
            }
        }
    }

    // ---- GEMM3 (wave 0 only): conf = relu(mf @ Wf1 + bf1) @ Wf2 + bf2 ----
    if (w == 0) {
        f32x4 acc[2][4];
#pragma unroll
        for (int mt = 0; mt < 2; ++mt)
#pragma unroll
            for (int nt = 0; nt < 4; ++nt) { f32x4 z = {0.f,0.f,0.f,0.f}; acc[mt][nt] = z; }
        for (int f0 = 0; f0 < HH; f0 += 32) {
            bf16x8 a0 = *(const bf16x8*)(mf + lane15 * RFP + f0 + quad * 8);
            bf16x8 a1 = *(const bf16x8*)(mf + (16 + lane15) * RFP + f0 + quad * 8);
#pragma unroll
            for (int nt = 0; nt < 4; ++nt) {
                const int n = nt * 16 + lane15;
                const float* bp = Wf1 + (f0 + quad * 8) * 64 + n;
                bf16x8 bf;
#pragma unroll
                for (int j = 0; j < 8; ++j) bf[j] = (__bf16)bp[j * 64];
                acc[0][nt] = __builtin_amdgcn_mfma_f32_16x16x32_bf16(a0, bf, acc[0][nt], 0, 0, 0);
                acc[1][nt] = __builtin_amdgcn_mfma_f32_16x16x32_bf16(a1, bf, acc[1][nt], 0, 0, 0);
            }
        }
        const float b2 = bf2v[0];
#pragma unroll
        for (int mt = 0; mt < 2; ++mt)
#pragma unroll
            for (int reg = 0; reg < 4; ++reg) {
                float s = 0.f;
#pragma unroll
                for (int nt = 0; nt < 4; ++nt) {
                    const int n = nt * 16 + lane15;
                    s = fmaf(fmaxf(acc[mt][nt][reg] + bf1[n], 0.f), Wf2[n], s);
                }
#pragma unroll
                for (int off = 1; off < 16; off <<= 1) s += __shfl_xor(s, off);
                if (lane15 == 0) {
                    int row = mt * 16 + quad * 4 + reg;
                    conf_out[(b0 + row) * KK + k] = s + b2;
                }
            }
    }
}

// ---------------- k_ef: per (b,k) traj+LN (Phase E) + refine MFMA (Phase F) ----------------
// 512 threads / 8 waves: same LDS (2 blocks/CU) but 16 waves/CU for latency hiding.
__launch_bounds__(512, 4)
__global__ void k_ef(
    const unsigned short* __restrict__ attn, const unsigned short* __restrict__ coarse_ws,
    const float* __restrict__ Wt,  const float* __restrict__ bt,
    const float* __restrict__ lng, const float* __restrict__ lnb,
    const unsigned short* __restrict__ Wr1T, const float* __restrict__ br1,
    const float* __restrict__ Wr2, const float* __restrict__ br2,
    float* __restrict__ pred_out)
{
    __shared__ __align__(16) unsigned short rf[64 * RFP];
    __shared__ float coarse[TO];
    __shared__ float po[64][2];

    const int tid = threadIdx.x;
    const int b = blockIdx.x / KK;
    const int k = blockIdx.x % KK;
    const int w = tid >> 6;          // 0..7
    const int ln = tid & 63;

    const unsigned short* attb = attn + b * HH;

    if (tid < TO) coarse[tid] = bf2f(coarse_ws[(b * KK + k) * TO + tid]);
    if (tid >= 128 && tid < 256) ((float*)po)[tid - 128] = 0.f;
    __syncthreads();

    // ---- Phase E: traj=gelu(coarse@Wt+bt); rf = LN(traj+attn)*g+b (bf16) ----
    {
        const int cbase = ln * 8;
        F8 w0 = load8f(Wt + cbase);
        F8 w1 = load8f(Wt + HH + cbase);
        F8 b8 = load8f(bt + cbase);
        F8 g8 = load8f(lng + cbase);
        F8 bb8 = load8f(lnb + cbase);
        F8 a8 = load8b(attb + cbase);
#pragma unroll
        for (int r = 0; r < 8; ++r) {
            int t = w + 8 * r;
            if (t < 60) {
                float co0 = coarse[2 * t], co1 = coarse[2 * t + 1];
                float x[8]; float s = 0.f, s2 = 0.f;
#pragma unroll
                for (int j = 0; j < 8; ++j) {
                    float vv = fmaf(co0, w0.v[j], fmaf(co1, w1.v[j], b8.v[j]));
                    vv = gelu_fast(vv) + a8.v[j];
                    x[j] = vv; s += vv; s2 = fmaf(vv, vv, s2);
                }
#pragma unroll
                for (int off = 32; off > 0; off >>= 1) {
                    s += __shfl_xor(s, off);
                    s2 += __shfl_xor(s2, off);
                }
                float mean = s * (1.0f / HH);
                float var = fmaf(-mean, mean, s2 * (1.0f / HH));
                float inv = rsqrtf(var + 1e-5f);
                unsigned int pk[4];
#pragma unroll
                for (int j = 0; j < 4; ++j) {
                    float y0 = fmaf((x[2 * j] - mean) * inv, g8.v[2 * j], bb8.v[2 * j]);
                    float y1 = fmaf((x[2 * j + 1] - mean) * inv, g8.v[2 * j + 1], bb8.v[2 * j + 1]);
                    pk[j] = (unsigned int)f2bf(y0) | ((unsigned int)f2bf(y1) << 16);
                }
                *(uint4*)(rf + t * RFP + cbase) = make_uint4(pk[0], pk[1], pk[2], pk[3]);
            } else {
                *(uint4*)(rf + t * RFP + cbase) = make_uint4(0, 0, 0, 0);
            }
        }
    }
    __syncthreads();

    // ---- Phase F: r=gelu(rf@Wr1+br1); offsets=r@Wr2 via MFMA ----
    {
        const unsigned short* wr1t_k = Wr1T + k * HH * HH;
        float po0[16], po1[16];
#pragma unroll
        for (int i = 0; i < 16; ++i) { po0[i] = 0.f; po1[i] = 0.f; }
        const int lane15 = ln & 15;
        const int quad = ln >> 4;
        const unsigned short* abase = rf + lane15 * RFP + quad * 8;

        for (int chunk = 0; chunk < 2; ++chunk) {
            const int n0 = w * 64 + chunk * 32;
            f32x4 acc[4][2];
#pragma unroll
            for (int rt = 0; rt < 4; ++rt) {
                f32x4 z = {0.f, 0.f, 0.f, 0.f};
                acc[rt][0] = z; acc[rt][1] = z;
            }
            const unsigned short* bp0 = wr1t_k + (n0 + lane15) * HH + quad * 8;
            const unsigned short* bp1 = bp0 + 16 * HH;
#pragma unroll 2
            for (int f0 = 0; f0 < HH; f0 += 32) {
                bf16x8 bfr0 = *(const bf16x8*)(bp0 + f0);
                bf16x8 bfr1 = *(const bf16x8*)(bp1 + f0);
#pragma unroll
                for (int rt = 0; rt < 4; ++rt) {
                    bf16x8 af = *(const bf16x8*)(abase + rt * 16 * RFP + f0);
                    acc[rt][0] = __builtin_amdgcn_mfma_f32_16x16x32_bf16(af, bfr0, acc[rt][0], 0, 0, 0);
                    acc[rt][1] = __builtin_amdgcn_mfma_f32_16x16x32_bf16(af, bfr1, acc[rt][1], 0, 0, 0);
                }
            }
#pragma unroll
            for (int nt = 0; nt < 2; ++nt) {
                const int col = n0 + nt * 16 + lane15;
                const float bb1 = br1[k * HH + col];
                const float w20 = Wr2[(k * HH + col) * 2];
                const float w21 = Wr2[(k * HH + col) * 2 + 1];
#pragma unroll
                for (int rt = 0; rt < 4; ++rt)
#pragma unroll
                    for (int i = 0; i < 4; ++i) {
                        float rv = gelu_fast(acc[rt][nt][i] + bb1);
                        po0[rt * 4 + i] = fmaf(rv, w20, po0[rt * 4 + i]);
                        po1[rt * 4 + i] = fmaf(rv, w21, po1[rt * 4 + i]);
                    }
            }
        }
#pragma unroll
        for (int off = 1; off < 16; off <<= 1) {
#pragma unroll
            for (int i = 0; i < 16; ++i) {
                po0[i] += __shfl_xor(po0[i], off);
                po1[i] += __shfl_xor(po1[i], off);
            }
        }
        if (lane15 == 0) {
#pragma unroll
            for (int i = 0; i < 16; ++i) {
                int row = (i / 4) * 16 + quad * 4 + (i % 4);
                atomicAdd(&po[row][0], po0[i]);
                atomicAdd(&po[row][1], po1[i]);
            }
        }
    }
    __syncthreads();

    // ---- predictions = coarse + offsets + br2 (fp32 out) ----
    if (tid < TO) {
        int t = tid >> 1, o = tid & 1;
        float v = coarse[tid] + po[t][o] + br2[k * 2 + o];
        pred_out[((b * KK + k) * TT + t) * 2 + o] = v;
    }
}

// ---------------- softmax over K for mode_probs (fp32 out) ----------------
__global__ void k_softmax(const float* __restrict__ conf, float* __restrict__ out) {
    int b = blockIdx.x * blockDim.x + threadIdx.x;
    if (b < BB) {
        float v[KK];
        float m = -1e30f;
        for (int i = 0; i < KK; ++i) { v[i] = conf[b * KK + i]; m = fmaxf(m, v[i]); }
        float s = 0.f;
        for (int i = 0; i < KK; ++i) { v[i] = expf(v[i] - m); s += v[i]; }
        float inv = 1.0f / s;
        for (int i = 0; i < KK; ++i) out[b * KK + i] = v[i] * inv;
    }
}

extern "C" void kernel_launch(void* const* d_in, const int* in_sizes, int n_in,
                              void* d_out, int out_size, void* d_ws, size_t ws_size,
                              hipStream_t stream) {
    const float* I0  = (const float*)d_in[0];
    const float* I1  = (const float*)d_in[1];
    const float* I2  = (const float*)d_in[2];
    const float* MQ  = (const float*)d_in[3];
    const float* Wc1 = (const float*)d_in[4];
    const float* bc1 = (const float*)d_in[5];
    const float* Wc2 = (const float*)d_in[6];
    const float* bc2 = (const float*)d_in[7];
    const float* Wk1 = (const float*)d_in[8];
    const float* bk1 = (const float*)d_in[9];
    const float* Wk2 = (const float*)d_in[10];
    const float* bk2 = (const float*)d_in[11];
    const float* Wt  = (const float*)d_in[12];
    const float* bt  = (const float*)d_in[13];
    const float* Wv  = (const float*)d_in[18];
    const float* bv  = (const float*)d_in[19];
    const float* Wo  = (const float*)d_in[20];
    const float* bo  = (const float*)d_in[21];
    const float* lng = (const float*)d_in[22];
    const float* lnb = (const float*)d_in[23];
    const float* Wr1 = (const float*)d_in[24];
    const float* br1 = (const float*)d_in[25];
    const float* Wr2 = (const float*)d_in[26];
    const float* br2 = (const float*)d_in[27];
    const float* Wf1 = (const float*)d_in[28];
    const float* bf1 = (const float*)d_in[29];
    const float* Wf2 = (const float*)d_in[30];
    const float* bf2v = (const float*)d_in[31];

    // ws layout (4.94 MB), ushort units:
    //   wr1t   [0 .. 1,572,864)         3 MB bf16; first 512 KB doubles as g1/vbuf tmp
    //   ctx    [1,572,864 .. +262,144)  bf16
    //   attn   [1,835,008 .. +262,144)  bf16
    //   coarse [2,097,152 .. +368,640)  bf16 (B,K,120)
    //   conf   byte 4,931,584 .. +12,288 fp32
    unsigned short* wsu   = (unsigned short*)d_ws;
    unsigned short* wr1t  = wsu;
    unsigned short* tmp   = wsu;                       // g1/vbuf alias (dead before transpose)
    unsigned short* ctx   = wsu + 1572864;
    unsigned short* attn  = wsu + 1835008;
    unsigned short* coarse= wsu + 2097152;
    float* conf = (float*)(wsu + 2465792);

    float* pred = (float*)d_out;
    float* probs = pred + BB * KK * TT * OO;

    k_gemm_m<true,  true ><<<dim3(16, 8), 256, 0, stream>>>(I0, I1, I2, Wc1, bc1, tmp, 3);
    k_gemm_m<false, false><<<dim3(16, 8), 256, 0, stream>>>(tmp, nullptr, nullptr, Wc2, bc2, ctx, 1);
    k_gemm_m<false, false><<<dim3(16, 8), 256, 0, stream>>>(ctx, nullptr, nullptr, Wv, bv, tmp, 1);
    k_gemm_m<false, false><<<dim3(16, 8), 256, 0, stream>>>(tmp, nullptr, nullptr, Wo, bo, attn, 1);
    k_transpose<<<dim3(16, 16, 6), 256, 0, stream>>>(Wr1, wr1t);   // after tmp is dead
    k_bc<<<dim3(96), 256, 0, stream>>>(ctx, MQ, Wk1, bk1, Wk2, bk2, Wf1, bf1, Wf2, bf2v,
                                       coarse, conf);
    k_ef<<<dim3(BB * KK), 512, 0, stream>>>(attn, coarse, Wt, bt, lng, lnb,
                                            wr1t, br1, Wr2, br2, pred);
    k_softmax<<<dim3(2), 256, 0, stream>>>(conf, probs);
}

// Round 7
// 509.454 us; speedup vs baseline: 2.2571x; 1.1603x over previous
//
#include <hip/hip_runtime.h>
#include <math.h>

#define BB 512
#define HH 512
#define KK 6
#define TT 60
#define OO 2
#define H2 1024
#define TO 120
#define RFP 520   // padded LDS row stride (bf16 elems)
#define HSP 1032  // padded h row stride (bf16 elems)

typedef __bf16 bf16x8 __attribute__((ext_vector_type(8)));
typedef float  f32x4  __attribute__((ext_vector_type(4)));

__device__ __forceinline__ float bf2f(unsigned short u) {
    union { unsigned int i; float f; } v; v.i = ((unsigned int)u) << 16; return v.f;
}
__device__ __forceinline__ unsigned short f2bf(float f) {
    union { float f; unsigned int i; } v; v.f = f;
    unsigned int b = v.i;
    return (unsigned short)((b + 0x7FFFu + ((b >> 16) & 1u)) >> 16); // RNE
}
__device__ __forceinline__ float gelu_exact(float x) {
    return 0.5f * x * (1.0f + erff(x * 0.70710678118654752f));
}
// tanh-approx GELU (max abs err ~3e-4): traj pre-LN and refine hidden only.
__device__ __forceinline__ float gelu_fast(float x) {
    float x3 = x * x * x;
    float z = fmaf(0.0713548162726f, x3, 1.5957691216057308f * x);
    return x / (1.0f + __expf(-z));
}

struct F8 { float v[8]; };
__device__ __forceinline__ F8 load8f(const float* p) {
    F8 r;
    float4 a = *(const float4*)p;
    float4 b = *(const float4*)(p + 4);
    r.v[0] = a.x; r.v[1] = a.y; r.v[2] = a.z; r.v[3] = a.w;
    r.v[4] = b.x; r.v[5] = b.y; r.v[6] = b.z; r.v[7] = b.w;
    return r;
}
__device__ __forceinline__ F8 load8b(const unsigned short* p) {
    ushort4 a = *(const ushort4*)p;
    ushort4 b = *(const ushort4*)(p + 4);
    F8 r;
    r.v[0] = bf2f(a.x); r.v[1] = bf2f(a.y); r.v[2] = bf2f(a.z); r.v[3] = bf2f(a.w);
    r.v[4] = bf2f(b.x); r.v[5] = bf2f(b.y); r.v[6] = bf2f(b.z); r.v[7] = bf2f(b.w);
    return r;
}

// ---- k_trans: fp32 [F][N] -> bf16 [N][F], batched over blockIdx.z ----
__global__ void k_trans(const float* __restrict__ in, unsigned short* __restrict__ out,
                        int F, int N) {
    __shared__ unsigned short t[32][33];
    const int f0 = blockIdx.x * 32, n0 = blockIdx.y * 32;
    const int r = threadIdx.x / 32, c = threadIdx.x % 32;
    in += (size_t)blockIdx.z * F * N;
    out += (size_t)blockIdx.z * F * N;
#pragma unroll
    for (int i = 0; i < 4; ++i) {
        int fr = f0 + r + 8 * i;
        if (fr < F && n0 + c < N) t[r + 8 * i][c] = f2bf(in[fr * N + n0 + c]);
    }
    __syncthreads();
#pragma unroll
    for (int i = 0; i < 4; ++i) {
        int nr = n0 + r + 8 * i;
        if (nr < N && f0 + c < F) out[nr * F + f0 + c] = t[c][r + 8 * i];
    }
}

// --------- MFMA ctx-chain GEMM: C(512x512 bf16) = [gelu](A @ B + bias) ---------
// BT is bf16 [n][f] (pre-transposed) -> B-frag is one contiguous 16B load,
// wave reads 16 rows x 64B fully coalesced (quads cover consecutive f).
template <bool CONCAT, bool GELU>
__launch_bounds__(256)
__global__ void k_gemm_m(const void* __restrict__ A0, const void* __restrict__ A1,
                         const void* __restrict__ A2, const unsigned short* __restrict__ BT,
                         const float* __restrict__ bias, unsigned short* __restrict__ C,
                         int Kd) {
    __shared__ __align__(16) unsigned short As[32 * RFP];
    const int tid = threadIdx.x;
    const int bm = blockIdx.x * 32;
    const int bn = blockIdx.y * 64;
    const int w = tid >> 6, ln = tid & 63;
    const int lane15 = ln & 15, quad = ln >> 4;
    const int n = bn + w * 16 + lane15;
    const int nchunks = Kd / HH;

    f32x4 acc0 = {0.f, 0.f, 0.f, 0.f}, acc1 = {0.f, 0.f, 0.f, 0.f};

    for (int kc = 0; kc < nchunks; ++kc) {
        {   // stage A rows bm..bm+31, cols [kc*512, +512) -> bf16 LDS
            int r = tid >> 3, c0 = (tid & 7) * 64;
            unsigned short* dp = As + r * RFP + c0;
            if (CONCAT) {
                const float* src = (kc == 0) ? (const float*)A0
                                 : (kc == 1) ? (const float*)A1 : (const float*)A2;
                const float* sp = src + (bm + r) * HH + c0;
                for (int c = 0; c < 64; c += 8) {
                    F8 v = load8f(sp + c);
                    unsigned int pk[4];
#pragma unroll
                    for (int j = 0; j < 4; ++j)
                        pk[j] = (unsigned int)f2bf(v.v[2 * j]) |
                                ((unsigned int)f2bf(v.v[2 * j + 1]) << 16);
                    *(uint4*)(dp + c) = make_uint4(pk[0], pk[1], pk[2], pk[3]);
                }
            } else {
                const unsigned short* sp = (const unsigned short*)A0 + (bm + r) * HH + c0;
                for (int c = 0; c < 64; c += 8)
                    *(uint4*)(dp + c) = *(const uint4*)(sp + c);
            }
        }
        __syncthreads();
        const unsigned short* bp = BT + (size_t)n * Kd + kc * HH + quad * 8;
#pragma unroll 4
        for (int f0 = 0; f0 < HH; f0 += 32) {
            bf16x8 a0 = *(const bf16x8*)(As + lane15 * RFP + f0 + quad * 8);
            bf16x8 a1 = *(const bf16x8*)(As + (16 + lane15) * RFP + f0 + quad * 8);
            bf16x8 bf = *(const bf16x8*)(bp + f0);
            acc0 = __builtin_amdgcn_mfma_f32_16x16x32_bf16(a0, bf, acc0, 0, 0, 0);
            acc1 = __builtin_amdgcn_mfma_f32_16x16x32_bf16(a1, bf, acc1, 0, 0, 0);
        }
        __syncthreads();
    }
    const float bb = bias[n];
#pragma unroll
    for (int reg = 0; reg < 4; ++reg) {
        float v0 = acc0[reg] + bb, v1 = acc1[reg] + bb;
        if (GELU) { v0 = gelu_exact(v0); v1 = gelu_exact(v1); }
        C[(bm + quad * 4 + reg) * HH + n] = f2bf(v0);
        C[(bm + 16 + quad * 4 + reg) * HH + n] = f2bf(v1);
    }
}

// ---------------- k_bc: batched coarse-heads + conf, per (k, 32 b-rows), 8 waves ----------------
__launch_bounds__(512)
__global__ void k_bc(const unsigned short* __restrict__ ctx, const float* __restrict__ mq,
                     const unsigned short* __restrict__ Wk1T, const float* __restrict__ bk1,
                     const unsigned short* __restrict__ Wk2T, const float* __restrict__ bk2,
                     const unsigned short* __restrict__ Wf1T, const float* __restrict__ bf1,
                     const float* __restrict__ Wf2, const float* __restrict__ bf2v,
                     unsigned short* __restrict__ coarse_out, float* __restrict__ conf_out)
{
    __shared__ __align__(16) unsigned short mf[32 * RFP];
    __shared__ __align__(16) unsigned short hs[32 * HSP];

    const int tid = threadIdx.x;
    const int k = blockIdx.x % KK;
    const int b0 = (blockIdx.x / KK) * 32;
    const int w = tid >> 6;            // 0..7
    const int ln = tid & 63;
    const int lane15 = ln & 15;
    const int quad = ln >> 4;

    // ---- stage mf = bf16(ctx + mq[k]) rows b0..b0+31 ----
    {
        int r = tid >> 4;              // 0..31
        int c0 = (tid & 15) * 32;
        const unsigned short* cp = ctx + (b0 + r) * HH + c0;
        const float* qp = mq + k * HH + c0;
        unsigned short* dp = mf + r * RFP + c0;
        for (int c = 0; c < 32; c += 8) {
            F8 cv = load8b(cp + c);
            F8 qv = load8f(qp + c);
            unsigned int pk[4];
#pragma unroll
            for (int j = 0; j < 4; ++j)
                pk[j] = (unsigned int)f2bf(cv.v[2 * j] + qv.v[2 * j]) |
                        ((unsigned int)f2bf(cv.v[2 * j + 1] + qv.v[2 * j + 1]) << 16);
            *(uint4*)(dp + c) = make_uint4(pk[0], pk[1], pk[2], pk[3]);
        }
    }
    __syncthreads();

    // ---- GEMM1: h = gelu(mf @ Wk1[k] + bk1[k]) -> hs. Per-wave n-slice 128. ----
    {
        const unsigned short* wk1t = Wk1T + (size_t)k * H2 * HH;  // [n<1024][f<512]
        const float* bk1p = bk1 + k * H2;
        for (int g = 0; g < 8; ++g) {
            const int n = w * 128 + g * 16 + lane15;
            f32x4 acc0 = {0.f,0.f,0.f,0.f}, acc1 = {0.f,0.f,0.f,0.f};
            const unsigned short* bp = wk1t + (size_t)n * HH + quad * 8;
#pragma unroll 4
            for (int f0 = 0; f0 < HH; f0 += 32) {
                bf16x8 a0 = *(const bf16x8*)(mf + lane15 * RFP + f0 + quad * 8);
                bf16x8 a1 = *(const bf16x8*)(mf + (16 + lane15) * RFP + f0 + quad * 8);
                bf16x8 bf = *(const bf16x8*)(bp + f0);
                acc0 = __builtin_amdgcn_mfma_f32_16x16x32_bf16(a0, bf, acc0, 0, 0, 0);
                acc1 = __builtin_amdgcn_mfma_f32_16x16x32_bf16(a1, bf, acc1, 0, 0, 0);
            }
            const float bias = bk1p[n];
#pragma unroll
            for (int reg = 0; reg < 4; ++reg) {
                hs[(quad * 4 + reg) * HSP + n] = f2bf(gelu_exact(acc0[reg] + bias));
                hs[(16 + quad * 4 + reg) * HSP + n] = f2bf(gelu_exact(acc1[reg] + bias));
            }
        }
    }
    __syncthreads();

    // ---- GEMM2: coarse = h @ Wk2[k] + bk2[k]. Per-wave n-tile 16 (8x16=128 >= 120). ----
    {
        const unsigned short* wk2t = Wk2T + (size_t)k * TO * H2;  // [n<120][f<1024]
        const int n = w * 16 + lane15;
        const int nc = (n < TO) ? n : (TO - 1);   // clamp address, guard store
        f32x4 acc0 = {0.f,0.f,0.f,0.f}, acc1 = {0.f,0.f,0.f,0.f};
        const unsigned short* bp = wk2t + (size_t)nc * H2 + quad * 8;
#pragma unroll 4
        for (int f0 = 0; f0 < H2; f0 += 32) {
            bf16x8 a0 = *(const bf16x8*)(hs + lane15 * HSP + f0 + quad * 8);
            bf16x8 a1 = *(const bf16x8*)(hs + (16 + lane15) * HSP + f0 + quad * 8);
            bf16x8 bf = *(const bf16x8*)(bp + f0);
            acc0 = __builtin_amdgcn_mfma_f32_16x16x32_bf16(a0, bf, acc0, 0, 0, 0);
            acc1 = __builtin_amdgcn_mfma_f32_16x16x32_bf16(a1, bf, acc1, 0, 0, 0);
        }
        if (n < TO) {
            const float bias = bk2[k * TO + n];
#pragma unroll
            for (int reg = 0; reg < 4; ++reg) {
                coarse_out[((b0 + quad * 4 + reg) * KK + k) * TO + n] = f2bf(acc0[reg] + bias);
                coarse_out[((b0 + 16 + quad * 4 + reg) * KK + k) * TO + n] = f2bf(acc1[reg] + bias);
            }
        }
    }

    // ---- GEMM3 (wave 0): conf = relu(mf @ Wf1 + bf1) @ Wf2 + bf2 ----
    if (w == 0) {
        f32x4 acc[2][4];
#pragma unroll
        for (int mt = 0; mt < 2; ++mt)
#pragma unroll
            for (int nt = 0; nt < 4; ++nt) { f32x4 z = {0.f,0.f,0.f,0.f}; acc[mt][nt] = z; }
        for (int f0 = 0; f0 < HH; f0 += 32) {
            bf16x8 a0 = *(const bf16x8*)(mf + lane15 * RFP + f0 + quad * 8);
            bf16x8 a1 = *(const bf16x8*)(mf + (16 + lane15) * RFP + f0 + quad * 8);
#pragma unroll
            for (int nt = 0; nt < 4; ++nt) {
                const int n = nt * 16 + lane15;
                bf16x8 bf = *(const bf16x8*)(Wf1T + (size_t)n * HH + f0 + quad * 8);
                acc[0][nt] = __builtin_amdgcn_mfma_f32_16x16x32_bf16(a0, bf, acc[0][nt], 0, 0, 0);
                acc[1][nt] = __builtin_amdgcn_mfma_f32_16x16x32_bf16(a1, bf, acc[1][nt], 0, 0, 0);
            }
        }
        const float b2 = bf2v[0];
#pragma unroll
        for (int mt = 0; mt < 2; ++mt)
#pragma unroll
            for (int reg = 0; reg < 4; ++reg) {
                float s = 0.f;
#pragma unroll
                for (int nt = 0; nt < 4; ++nt) {
                    const int n = nt * 16 + lane15;
                    s = fmaf(fmaxf(acc[mt][nt][reg] + bf1[n], 0.f), Wf2[n], s);
                }
#pragma unroll
                for (int off = 1; off < 16; off <<= 1) s += __shfl_xor(s, off);
                if (lane15 == 0) {
                    int row = mt * 16 + quad * 4 + reg;
                    conf_out[(b0 + row) * KK + k] = s + b2;
                }
            }
    }
}

// ---------------- k_ef: per (b,k) traj+LN (Phase E) + refine MFMA (Phase F) ----------------
__launch_bounds__(512, 4)
__global__ void k_ef(
    const unsigned short* __restrict__ attn, const unsigned short* __restrict__ coarse_ws,
    const float* __restrict__ Wt,  const float* __restrict__ bt,
    const float* __restrict__ lng, const float* __restrict__ lnb,
    const unsigned short* __restrict__ Wr1T, const float* __restrict__ br1,
    const float* __restrict__ Wr2, const float* __restrict__ br2,
    float* __restrict__ pred_out)
{
    __shared__ __align__(16) unsigned short rf[64 * RFP];
    __shared__ float coarse[TO];
    __shared__ float po[64][2];

    const int tid = threadIdx.x;
    const int b = blockIdx.x / KK;
    const int k = blockIdx.x % KK;
    const int w = tid >> 6;          // 0..7
    const int ln = tid & 63;

    const unsigned short* attb = attn + b * HH;

    if (tid < TO) coarse[tid] = bf2f(coarse_ws[(b * KK + k) * TO + tid]);
    if (tid >= 128 && tid < 256) ((float*)po)[tid - 128] = 0.f;
    __syncthreads();

    // ---- Phase E ----
    {
        const int cbase = ln * 8;
        F8 w0 = load8f(Wt + cbase);
        F8 w1 = load8f(Wt + HH + cbase);
        F8 b8 = load8f(bt + cbase);
        F8 g8 = load8f(lng + cbase);
        F8 bb8 = load8f(lnb + cbase);
        F8 a8 = load8b(attb + cbase);
#pragma unroll
        for (int r = 0; r < 8; ++r) {
            int t = w + 8 * r;
            if (t < 60) {
                float co0 = coarse[2 * t], co1 = coarse[2 * t + 1];
                float x[8]; float s = 0.f, s2 = 0.f;
#pragma unroll
                for (int j = 0; j < 8; ++j) {
                    float vv = fmaf(co0, w0.v[j], fmaf(co1, w1.v[j], b8.v[j]));
                    vv = gelu_fast(vv) + a8.v[j];
                    x[j] = vv; s += vv; s2 = fmaf(vv, vv, s2);
                }
#pragma unroll
                for (int off = 32; off > 0; off >>= 1) {
                    s += __shfl_xor(s, off);
                    s2 += __shfl_xor(s2, off);
                }
                float mean = s * (1.0f / HH);
                float var = fmaf(-mean, mean, s2 * (1.0f / HH));
                float inv = rsqrtf(var + 1e-5f);
                unsigned int pk[4];
#pragma unroll
                for (int j = 0; j < 4; ++j) {
                    float y0 = fmaf((x[2 * j] - mean) * inv, g8.v[2 * j], bb8.v[2 * j]);
                    float y1 = fmaf((x[2 * j + 1] - mean) * inv, g8.v[2 * j + 1], bb8.v[2 * j + 1]);
                    pk[j] = (unsigned int)f2bf(y0) | ((unsigned int)f2bf(y1) << 16);
                }
                *(uint4*)(rf + t * RFP + cbase) = make_uint4(pk[0], pk[1], pk[2], pk[3]);
            } else {
                *(uint4*)(rf + t * RFP + cbase) = make_uint4(0, 0, 0, 0);
            }
        }
    }
    __syncthreads();

    // ---- Phase F ----
    {
        const unsigned short* wr1t_k = Wr1T + (size_t)k * HH * HH;
        float po0[16], po1[16];
#pragma unroll
        for (int i = 0; i < 16; ++i) { po0[i] = 0.f; po1[i] = 0.f; }
        const int lane15 = ln & 15;
        const int quad = ln >> 4;
        const unsigned short* abase = rf + lane15 * RFP + quad * 8;

        for (int chunk = 0; chunk < 2; ++chunk) {
            const int n0 = w * 64 + chunk * 32;
            f32x4 acc[4][2];
#pragma unroll
            for (int rt = 0; rt < 4; ++rt) {
                f32x4 z = {0.f, 0.f, 0.f, 0.f};
                acc[rt][0] = z; acc[rt][1] = z;
            }
            const unsigned short* bp0 = wr1t_k + (n0 + lane15) * HH + quad * 8;
            const unsigned short* bp1 = bp0 + 16 * HH;
#pragma unroll 4
            for (int f0 = 0; f0 < HH; f0 += 32) {
                bf16x8 bfr0 = *(const bf16x8*)(bp0 + f0);
                bf16x8 bfr1 = *(const bf16x8*)(bp1 + f0);
#pragma unroll
                for (int rt = 0; rt < 4; ++rt) {
                    bf16x8 af = *(const bf16x8*)(abase + rt * 16 * RFP + f0);
                    acc[rt][0] = __builtin_amdgcn_mfma_f32_16x16x32_bf16(af, bfr0, acc[rt][0], 0, 0, 0);
                    acc[rt][1] = __builtin_amdgcn_mfma_f32_16x16x32_bf16(af, bfr1, acc[rt][1], 0, 0, 0);
                }
            }
#pragma unroll
            for (int nt = 0; nt < 2; ++nt) {
                const int col = n0 + nt * 16 + lane15;
                const float bb1 = br1[k * HH + col];
                const float w20 = Wr2[(k * HH + col) * 2];
                const float w21 = Wr2[(k * HH + col) * 2 + 1];
#pragma unroll
                for (int rt = 0; rt < 4; ++rt)
#pragma unroll
                    for (int i = 0; i < 4; ++i) {
                        float rv = gelu_fast(acc[rt][nt][i] + bb1);
                        po0[rt * 4 + i] = fmaf(rv, w20, po0[rt * 4 + i]);
                        po1[rt * 4 + i] = fmaf(rv, w21, po1[rt * 4 + i]);
                    }
            }
        }
#pragma unroll
        for (int off = 1; off < 16; off <<= 1) {
#pragma unroll
            for (int i = 0; i < 16; ++i) {
                po0[i] += __shfl_xor(po0[i], off);
                po1[i] += __shfl_xor(po1[i], off);
            }
        }
        if ((ln & 15) == 0) {
            const int quad = ln >> 4;
#pragma unroll
            for (int i = 0; i < 16; ++i) {
                int row = (i / 4) * 16 + quad * 4 + (i % 4);
                atomicAdd(&po[row][0], po0[i]);
                atomicAdd(&po[row][1], po1[i]);
            }
        }
    }
    __syncthreads();

    if (tid < TO) {
        int t = tid >> 1, o = tid & 1;
        float v = coarse[tid] + po[t][o] + br2[k * 2 + o];
        pred_out[((b * KK + k) * TT + t) * 2 + o] = v;
    }
}

// ---------------- softmax over K for mode_probs ----------------
__global__ void k_softmax(const float* __restrict__ conf, float* __restrict__ out) {
    int b = blockIdx.x * blockDim.x + threadIdx.x;
    if (b < BB) {
        float v[KK];
        float m = -1e30f;
        for (int i = 0; i < KK; ++i) { v[i] = conf[b * KK + i]; m = fmaxf(m, v[i]); }
        float s = 0.f;
        for (int i = 0; i < KK; ++i) { v[i] = __expf(v[i] - m); s += v[i]; }
        float inv = 1.0f / s;
        for (int i = 0; i < KK; ++i) out[b * KK + i] = v[i] * inv;
    }
}

extern "C" void kernel_launch(void* const* d_in, const int* in_sizes, int n_in,
                              void* d_out, int out_size, void* d_ws, size_t ws_size,
                              hipStream_t stream) {
    const float* I0  = (const float*)d_in[0];
    const float* I1  = (const float*)d_in[1];
    const float* I2  = (const float*)d_in[2];
    const float* MQ  = (const float*)d_in[3];
    const float* Wc1 = (const float*)d_in[4];
    const float* bc1 = (const float*)d_in[5];
    const float* Wc2 = (const float*)d_in[6];
    const float* bc2 = (const float*)d_in[7];
    const float* Wk1 = (const float*)d_in[8];
    const float* bk1 = (const float*)d_in[9];
    const float* Wk2 = (const float*)d_in[10];
    const float* bk2 = (const float*)d_in[11];
    const float* Wt  = (const float*)d_in[12];
    const float* bt  = (const float*)d_in[13];
    const float* Wv  = (const float*)d_in[18];
    const float* bv  = (const float*)d_in[19];
    const float* Wo  = (const float*)d_in[20];
    const float* bo  = (const float*)d_in[21];
    const float* lng = (const float*)d_in[22];
    const float* lnb = (const float*)d_in[23];
    const float* Wr1 = (const float*)d_in[24];
    const float* br1 = (const float*)d_in[25];
    const float* Wr2 = (const float*)d_in[26];
    const float* br2 = (const float*)d_in[27];
    const float* Wf1 = (const float*)d_in[28];
    const float* bf1 = (const float*)d_in[29];
    const float* Wf2 = (const float*)d_in[30];
    const float* bf2v = (const float*)d_in[31];

    // ws layout (ushort units), ~15.7 MB total:
    unsigned short* wsu   = (unsigned short*)d_ws;
    unsigned short* wc1t  = wsu;                 // 786,432   [512][1536]
    unsigned short* wc2t  = wsu + 786432;        // 262,144   [512][512]
    unsigned short* wvt   = wsu + 1048576;       // 262,144
    unsigned short* wot   = wsu + 1310720;       // 262,144
    unsigned short* wk1t  = wsu + 1572864;       // 3,145,728 (K)[1024][512]
    unsigned short* wk2t  = wsu + 4718592;       // 737,280   (K)[120][1024]
    unsigned short* wf1t  = wsu + 5455872;       // 32,768    [64][512]
    unsigned short* wr1t  = wsu + 5488640;       // 1,572,864 (K)[512][512]
    unsigned short* ctx   = wsu + 7061504;       // 262,144
    unsigned short* attn  = wsu + 7323648;       // 262,144
    unsigned short* tmp   = wsu + 7585792;       // 262,144 (g1 / vbuf)
    unsigned short* coarse= wsu + 7847936;       // 368,640 (B,K,120)
    float* conf = (float*)(wsu + 8216576);       // 3072 fp32

    float* pred = (float*)d_out;
    float* probs = pred + BB * KK * TT * OO;

    // -- prep: all weights -> bf16 [n][f] --
    k_trans<<<dim3(48, 16, 1), 256, 0, stream>>>(Wc1, wc1t, 3 * HH, HH);
    k_trans<<<dim3(16, 16, 1), 256, 0, stream>>>(Wc2, wc2t, HH, HH);
    k_trans<<<dim3(16, 16, 1), 256, 0, stream>>>(Wv,  wvt,  HH, HH);
    k_trans<<<dim3(16, 16, 1), 256, 0, stream>>>(Wo,  wot,  HH, HH);
    k_trans<<<dim3(16, 32, 6), 256, 0, stream>>>(Wk1, wk1t, HH, H2);
    k_trans<<<dim3(32, 4, 6),  256, 0, stream>>>(Wk2, wk2t, H2, TO);
    k_trans<<<dim3(16, 2, 1),  256, 0, stream>>>(Wf1, wf1t, HH, 64);
    k_trans<<<dim3(16, 16, 6), 256, 0, stream>>>(Wr1, wr1t, HH, HH);

    // -- ctx chain --
    k_gemm_m<true,  true ><<<dim3(16, 8), 256, 0, stream>>>(I0, I1, I2, wc1t, bc1, tmp, 3 * HH);
    k_gemm_m<false, false><<<dim3(16, 8), 256, 0, stream>>>(tmp, nullptr, nullptr, wc2t, bc2, ctx, HH);
    k_gemm_m<false, false><<<dim3(16, 8), 256, 0, stream>>>(ctx, nullptr, nullptr, wvt, bv, tmp, HH);
    k_gemm_m<false, false><<<dim3(16, 8), 256, 0, stream>>>(tmp, nullptr, nullptr, wot, bo, attn, HH);

    k_bc<<<dim3(96), 512, 0, stream>>>(ctx, MQ, wk1t, bk1, wk2t, bk2, wf1t, bf1, Wf2, bf2v,
                                       coarse, conf);
    k_ef<<<dim3(BB * KK), 512, 0, stream>>>(attn, coarse, Wt, bt, lng, lnb,
                                            wr1t, br1, Wr2, br2, pred);
    k_softmax<<<dim3(2), 256, 0, stream>>>(conf, probs);
}

// Round 8
// 485.164 us; speedup vs baseline: 2.3701x; 1.0501x over previous
//
#include <hip/hip_runtime.h>
#include <math.h>

#define BB 512
#define HH 512
#define KK 6
#define TT 60
#define OO 2
#define H2 1024
#define TO 120
#define RFP 520   // padded LDS row stride (bf16 elems), 1040B = 65x16B
#define HSP 1032  // padded h row stride (bf16 elems)

typedef __bf16 bf16x8 __attribute__((ext_vector_type(8)));
typedef float  f32x4  __attribute__((ext_vector_type(4)));
typedef float  f32x16 __attribute__((ext_vector_type(16)));

__device__ __forceinline__ float bf2f(unsigned short u) {
    union { unsigned int i; float f; } v; v.i = ((unsigned int)u) << 16; return v.f;
}
__device__ __forceinline__ unsigned short f2bf(float f) {
    union { float f; unsigned int i; } v; v.f = f;
    unsigned int b = v.i;
    return (unsigned short)((b + 0x7FFFu + ((b >> 16) & 1u)) >> 16); // RNE
}
__device__ __forceinline__ float gelu_exact(float x) {
    return 0.5f * x * (1.0f + erff(x * 0.70710678118654752f));
}

#if defined(__has_builtin)
#  if __has_builtin(__builtin_amdgcn_rcpf)
#    define FAST_RCP(x) __builtin_amdgcn_rcpf(x)
#  endif
#  if __has_builtin(__builtin_amdgcn_exp2f)
#    define FAST_EXP2(x) __builtin_amdgcn_exp2f(x)
#  endif
#endif
#ifndef FAST_RCP
#  define FAST_RCP(x) (1.0f / (x))
#endif
#ifndef FAST_EXP2
#  define FAST_EXP2(x) __expf((x) * 0.69314718056f)
#endif

// tanh-form GELU, constants pre-scaled by log2(e); ~7 VALU inst.
// max abs err ~3e-4 vs exact erf (same approx family as round 5/6, passing).
__device__ __forceinline__ float gelu_cheap(float x) {
    float x2 = x * x;
    float z = x * fmaf(0.10294324f, x2, 2.3022082f);
    float e = FAST_EXP2(-z);
    return x * FAST_RCP(1.0f + e);
}

struct F8 { float v[8]; };
__device__ __forceinline__ F8 load8f(const float* p) {
    F8 r;
    float4 a = *(const float4*)p;
    float4 b = *(const float4*)(p + 4);
    r.v[0] = a.x; r.v[1] = a.y; r.v[2] = a.z; r.v[3] = a.w;
    r.v[4] = b.x; r.v[5] = b.y; r.v[6] = b.z; r.v[7] = b.w;
    return r;
}
__device__ __forceinline__ F8 load8b(const unsigned short* p) {
    ushort4 a = *(const ushort4*)p;
    ushort4 b = *(const ushort4*)(p + 4);
    F8 r;
    r.v[0] = bf2f(a.x); r.v[1] = bf2f(a.y); r.v[2] = bf2f(a.z); r.v[3] = bf2f(a.w);
    r.v[4] = bf2f(b.x); r.v[5] = bf2f(b.y); r.v[6] = bf2f(b.z); r.v[7] = bf2f(b.w);
    return r;
}

// ---- fused transpose: 8 weight tensors fp32 [F][N](xZ) -> bf16 [N][F] in one launch ----
struct TD { const float* src; unsigned short* dst; int F, N, tiles; };
struct TD8 { TD e[8]; };

__global__ void k_trans_all(TD8 d) {
    __shared__ unsigned short t[32][33];
    int idx = blockIdx.x;
    int i = 0;
    while (i < 7 && idx >= d.e[i].tiles) { idx -= d.e[i].tiles; ++i; }
    const int F = d.e[i].F, N = d.e[i].N;
    const int tx = F >> 5, ty = (N + 31) >> 5;
    const int per = tx * ty;
    const int z = idx / per; idx -= z * per;
    const int fx = (idx % tx) * 32, ny = (idx / tx) * 32;
    const float* src = d.e[i].src + (size_t)z * F * N;
    unsigned short* dst = d.e[i].dst + (size_t)z * F * N;
    const int r = threadIdx.x / 32, c = threadIdx.x % 32;
#pragma unroll
    for (int q = 0; q < 4; ++q) {
        int fr = fx + r + 8 * q;
        if (ny + c < N) t[r + 8 * q][c] = f2bf(src[(size_t)fr * N + ny + c]);
    }
    __syncthreads();
#pragma unroll
    for (int q = 0; q < 4; ++q) {
        int nr = ny + r + 8 * q;
        if (nr < N) dst[(size_t)nr * F + fx + c] = t[c][r + 8 * q];
    }
}

// --------- MFMA ctx-chain GEMM: C(512x512 bf16) = [gelu](A @ B + bias) ---------
template <bool CONCAT, bool GELU>
__launch_bounds__(256)
__global__ void k_gemm_m(const void* __restrict__ A0, const void* __restrict__ A1,
                         const void* __restrict__ A2, const unsigned short* __restrict__ BT,
                         const float* __restrict__ bias, unsigned short* __restrict__ C,
                         int Kd) {
    __shared__ __align__(16) unsigned short As[32 * RFP];
    const int tid = threadIdx.x;
    const int bm = blockIdx.x * 32;
    const int bn = blockIdx.y * 64;
    const int w = tid >> 6, ln = tid & 63;
    const int lane15 = ln & 15, quad = ln >> 4;
    const int n = bn + w * 16 + lane15;
    const int nchunks = Kd / HH;

    f32x4 acc0 = {0.f, 0.f, 0.f, 0.f}, acc1 = {0.f, 0.f, 0.f, 0.f};

    for (int kc = 0; kc < nchunks; ++kc) {
        {
            int r = tid >> 3, c0 = (tid & 7) * 64;
            unsigned short* dp = As + r * RFP + c0;
            if (CONCAT) {
                const float* src = (kc == 0) ? (const float*)A0
                                 : (kc == 1) ? (const float*)A1 : (const float*)A2;
                const float* sp = src + (bm + r) * HH + c0;
                for (int c = 0; c < 64; c += 8) {
                    F8 v = load8f(sp + c);
                    unsigned int pk[4];
#pragma unroll
                    for (int j = 0; j < 4; ++j)
                        pk[j] = (unsigned int)f2bf(v.v[2 * j]) |
                                ((unsigned int)f2bf(v.v[2 * j + 1]) << 16);
                    *(uint4*)(dp + c) = make_uint4(pk[0], pk[1], pk[2], pk[3]);
                }
            } else {
                const unsigned short* sp = (const unsigned short*)A0 + (bm + r) * HH + c0;
                for (int c = 0; c < 64; c += 8)
                    *(uint4*)(dp + c) = *(const uint4*)(sp + c);
            }
        }
        __syncthreads();
        const unsigned short* bp = BT + (size_t)n * Kd + kc * HH + quad * 8;
        for (int f0 = 0; f0 < HH; f0 += 32) {
            bf16x8 a0 = *(const bf16x8*)(As + lane15 * RFP + f0 + quad * 8);
            bf16x8 a1 = *(const bf16x8*)(As + (16 + lane15) * RFP + f0 + quad * 8);
            bf16x8 bf = *(const bf16x8*)(bp + f0);
            acc0 = __builtin_amdgcn_mfma_f32_16x16x32_bf16(a0, bf, acc0, 0, 0, 0);
            acc1 = __builtin_amdgcn_mfma_f32_16x16x32_bf16(a1, bf, acc1, 0, 0, 0);
        }
        __syncthreads();
    }
    const float bb = bias[n];
#pragma unroll
    for (int reg = 0; reg < 4; ++reg) {
        float v0 = acc0[reg] + bb, v1 = acc1[reg] + bb;
        if (GELU) { v0 = gelu_exact(v0); v1 = gelu_exact(v1); }
        C[(bm + quad * 4 + reg) * HH + n] = f2bf(v0);
        C[(bm + 16 + quad * 4 + reg) * HH + n] = f2bf(v1);
    }
}

// ---------------- k_bc: batched coarse-heads + conf, per (k, 32 b-rows), 8 waves ----------------
__launch_bounds__(512)
__global__ void k_bc(const unsigned short* __restrict__ ctx, const float* __restrict__ mq,
                     const unsigned short* __restrict__ Wk1T, const float* __restrict__ bk1,
                     const unsigned short* __restrict__ Wk2T, const float* __restrict__ bk2,
                     const unsigned short* __restrict__ Wf1T, const float* __restrict__ bf1,
                     const float* __restrict__ Wf2, const float* __restrict__ bf2v,
                     unsigned short* __restrict__ coarse_out, float* __restrict__ conf_out)
{
    __shared__ __align__(16) unsigned short mf[32 * RFP];
    __shared__ __align__(16) unsigned short hs[32 * HSP];

    const int tid = threadIdx.x;
    const int k = blockIdx.x % KK;
    const int b0 = (blockIdx.x / KK) * 32;
    const int w = tid >> 6;
    const int ln = tid & 63;
    const int lane15 = ln & 15;
    const int quad = ln >> 4;

    {
        int r = tid >> 4;
        int c0 = (tid & 15) * 32;
        const unsigned short* cp = ctx + (b0 + r) * HH + c0;
        const float* qp = mq + k * HH + c0;
        unsigned short* dp = mf + r * RFP + c0;
        for (int c = 0; c < 32; c += 8) {
            F8 cv = load8b(cp + c);
            F8 qv = load8f(qp + c);
            unsigned int pk[4];
#pragma unroll
            for (int j = 0; j < 4; ++j)
                pk[j] = (unsigned int)f2bf(cv.v[2 * j] + qv.v[2 * j]) |
                        ((unsigned int)f2bf(cv.v[2 * j + 1] + qv.v[2 * j + 1]) << 16);
            *(uint4*)(dp + c) = make_uint4(pk[0], pk[1], pk[2], pk[3]);
        }
    }
    __syncthreads();

    {
        const unsigned short* wk1t = Wk1T + (size_t)k * H2 * HH;
        const float* bk1p = bk1 + k * H2;
        for (int g = 0; g < 8; ++g) {
            const int n = w * 128 + g * 16 + lane15;
            f32x4 acc0 = {0.f,0.f,0.f,0.f}, acc1 = {0.f,0.f,0.f,0.f};
            const unsigned short* bp = wk1t + (size_t)n * HH + quad * 8;
            for (int f0 = 0; f0 < HH; f0 += 32) {
                bf16x8 a0 = *(const bf16x8*)(mf + lane15 * RFP + f0 + quad * 8);
                bf16x8 a1 = *(const bf16x8*)(mf + (16 + lane15) * RFP + f0 + quad * 8);
                bf16x8 bf = *(const bf16x8*)(bp + f0);
                acc0 = __builtin_amdgcn_mfma_f32_16x16x32_bf16(a0, bf, acc0, 0, 0, 0);
                acc1 = __builtin_amdgcn_mfma_f32_16x16x32_bf16(a1, bf, acc1, 0, 0, 0);
            }
            const float bias = bk1p[n];
#pragma unroll
            for (int reg = 0; reg < 4; ++reg) {
                hs[(quad * 4 + reg) * HSP + n] = f2bf(gelu_exact(acc0[reg] + bias));
                hs[(16 + quad * 4 + reg) * HSP + n] = f2bf(gelu_exact(acc1[reg] + bias));
            }
        }
    }
    __syncthreads();

    {
        const unsigned short* wk2t = Wk2T + (size_t)k * TO * H2;
        const int n = w * 16 + lane15;
        const int nc = (n < TO) ? n : (TO - 1);
        f32x4 acc0 = {0.f,0.f,0.f,0.f}, acc1 = {0.f,0.f,0.f,0.f};
        const unsigned short* bp = wk2t + (size_t)nc * H2 + quad * 8;
        for (int f0 = 0; f0 < H2; f0 += 32) {
            bf16x8 a0 = *(const bf16x8*)(hs + lane15 * HSP + f0 + quad * 8);
            bf16x8 a1 = *(const bf16x8*)(hs + (16 + lane15) * HSP + f0 + quad * 8);
            bf16x8 bf = *(const bf16x8*)(bp + f0);
            acc0 = __builtin_amdgcn_mfma_f32_16x16x32_bf16(a0, bf, acc0, 0, 0, 0);
            acc1 = __builtin_amdgcn_mfma_f32_16x16x32_bf16(a1, bf, acc1, 0, 0, 0);
        }
        if (n < TO) {
            const float bias = bk2[k * TO + n];
#pragma unroll
            for (int reg = 0; reg < 4; ++reg) {
                coarse_out[((b0 + quad * 4 + reg) * KK + k) * TO + n] = f2bf(acc0[reg] + bias);
                coarse_out[((b0 + 16 + quad * 4 + reg) * KK + k) * TO + n] = f2bf(acc1[reg] + bias);
            }
        }
    }

    if (w == 0) {
        f32x4 acc[2][4];
#pragma unroll
        for (int mt = 0; mt < 2; ++mt)
#pragma unroll
            for (int nt = 0; nt < 4; ++nt) { f32x4 z = {0.f,0.f,0.f,0.f}; acc[mt][nt] = z; }
        for (int f0 = 0; f0 < HH; f0 += 32) {
            bf16x8 a0 = *(const bf16x8*)(mf + lane15 * RFP + f0 + quad * 8);
            bf16x8 a1 = *(const bf16x8*)(mf + (16 + lane15) * RFP + f0 + quad * 8);
#pragma unroll
            for (int nt = 0; nt < 4; ++nt) {
                const int n = nt * 16 + lane15;
                bf16x8 bf = *(const bf16x8*)(Wf1T + (size_t)n * HH + f0 + quad * 8);
                acc[0][nt] = __builtin_amdgcn_mfma_f32_16x16x32_bf16(a0, bf, acc[0][nt], 0, 0, 0);
                acc[1][nt] = __builtin_amdgcn_mfma_f32_16x16x32_bf16(a1, bf, acc[1][nt], 0, 0, 0);
            }
        }
        const float b2 = bf2v[0];
#pragma unroll
        for (int mt = 0; mt < 2; ++mt)
#pragma unroll
            for (int reg = 0; reg < 4; ++reg) {
                float s = 0.f;
#pragma unroll
                for (int nt = 0; nt < 4; ++nt) {
                    const int n = nt * 16 + lane15;
                    s = fmaf(fmaxf(acc[mt][nt][reg] + bf1[n], 0.f), Wf2[n], s);
                }
#pragma unroll
                for (int off = 1; off < 16; off <<= 1) s += __shfl_xor(s, off);
                if (lane15 == 0) {
                    int row = mt * 16 + quad * 4 + reg;
                    conf_out[(b0 + row) * KK + k] = s + b2;
                }
            }
    }
}

// ---------------- k_ef: per (b,k) traj+LN (Phase E) + refine via 32x32x16 MFMA (Phase F) ----------------
__launch_bounds__(512, 4)
__global__ void k_ef(
    const unsigned short* __restrict__ attn, const unsigned short* __restrict__ coarse_ws,
    const float* __restrict__ Wt,  const float* __restrict__ bt,
    const float* __restrict__ lng, const float* __restrict__ lnb,
    const unsigned short* __restrict__ Wr1T, const float* __restrict__ br1,
    const float* __restrict__ Wr2, const float* __restrict__ br2,
    float* __restrict__ pred_out)
{
    __shared__ __align__(16) unsigned short rf[64 * RFP];
    __shared__ float coarse[TO];
    __shared__ float po[64][2];

    const int tid = threadIdx.x;
    const int b = blockIdx.x / KK;
    const int k = blockIdx.x % KK;
    const int w = tid >> 6;          // 0..7
    const int ln = tid & 63;

    const unsigned short* attb = attn + b * HH;

    if (tid < TO) coarse[tid] = bf2f(coarse_ws[(b * KK + k) * TO + tid]);
    if (tid >= 128 && tid < 256) ((float*)po)[tid - 128] = 0.f;
    __syncthreads();

    // ---- Phase E: traj=gelu(coarse@Wt+bt); rf = LN(traj+attn)*g+b (bf16) ----
    {
        const int cbase = ln * 8;
        F8 w0 = load8f(Wt + cbase);
        F8 w1 = load8f(Wt + HH + cbase);
        F8 b8 = load8f(bt + cbase);
        F8 g8 = load8f(lng + cbase);
        F8 bb8 = load8f(lnb + cbase);
        F8 a8 = load8b(attb + cbase);
#pragma unroll
        for (int r = 0; r < 8; ++r) {
            int t = w + 8 * r;
            if (t < 60) {
                float co0 = coarse[2 * t], co1 = coarse[2 * t + 1];
                float x[8]; float s = 0.f, s2 = 0.f;
#pragma unroll
                for (int j = 0; j < 8; ++j) {
                    float vv = fmaf(co0, w0.v[j], fmaf(co1, w1.v[j], b8.v[j]));
                    vv = gelu_cheap(vv) + a8.v[j];
                    x[j] = vv; s += vv; s2 = fmaf(vv, vv, s2);
                }
#pragma unroll
                for (int off = 32; off > 0; off >>= 1) {
                    s += __shfl_xor(s, off);
                    s2 += __shfl_xor(s2, off);
                }
                float mean = s * (1.0f / HH);
                float var = fmaf(-mean, mean, s2 * (1.0f / HH));
                float inv = rsqrtf(var + 1e-5f);
                unsigned int pk[4];
#pragma unroll
                for (int j = 0; j < 4; ++j) {
                    float y0 = fmaf((x[2 * j] - mean) * inv, g8.v[2 * j], bb8.v[2 * j]);
                    float y1 = fmaf((x[2 * j + 1] - mean) * inv, g8.v[2 * j + 1], bb8.v[2 * j + 1]);
                    pk[j] = (unsigned int)f2bf(y0) | ((unsigned int)f2bf(y1) << 16);
                }
                *(uint4*)(rf + t * RFP + cbase) = make_uint4(pk[0], pk[1], pk[2], pk[3]);
            } else {
                *(uint4*)(rf + t * RFP + cbase) = make_uint4(0, 0, 0, 0);
            }
        }
    }
    __syncthreads();

    // ---- Phase F: r=gelu(rf@Wr1+br1); offsets=r@Wr2  (32x32x16 MFMA) ----
    // A[m=lane&31][k=(lane>>5)*8+j], B[n=lane&31][k=(lane>>5)*8+j],
    // C/D col=lane&31, row=(reg&3)+8*(reg>>2)+4*(lane>>5)  [m74/m101]
    {
        const unsigned short* wr1t_k = Wr1T + (size_t)k * HH * HH;
        const int lane31 = ln & 31;
        const int hf = ln >> 5;
        const int n0 = w * 64;
        const unsigned short* a0p = rf + lane31 * RFP + hf * 8;
        const unsigned short* a1p = a0p + 32 * RFP;
        const unsigned short* b0p = wr1t_k + (size_t)(n0 + lane31) * HH + hf * 8;
        const unsigned short* b1p = b0p + (size_t)32 * HH;

        f32x16 acc00 = {0.f,0.f,0.f,0.f,0.f,0.f,0.f,0.f,0.f,0.f,0.f,0.f,0.f,0.f,0.f,0.f};
        f32x16 acc01 = acc00, acc10 = acc00, acc11 = acc00;

#pragma unroll 2
        for (int k0 = 0; k0 < HH; k0 += 16) {
            bf16x8 A0 = *(const bf16x8*)(a0p + k0);
            bf16x8 A1 = *(const bf16x8*)(a1p + k0);
            bf16x8 B0 = *(const bf16x8*)(b0p + k0);
            bf16x8 B1 = *(const bf16x8*)(b1p + k0);
            acc00 = __builtin_amdgcn_mfma_f32_32x32x16_bf16(A0, B0, acc00, 0, 0, 0);
            acc01 = __builtin_amdgcn_mfma_f32_32x32x16_bf16(A0, B1, acc01, 0, 0, 0);
            acc10 = __builtin_amdgcn_mfma_f32_32x32x16_bf16(A1, B0, acc10, 0, 0, 0);
            acc11 = __builtin_amdgcn_mfma_f32_32x32x16_bf16(A1, B1, acc11, 0, 0, 0);
        }

        const int col0 = n0 + lane31;
        const int col1 = col0 + 32;
        const float bb0 = br1[k * HH + col0];
        const float bb1v = br1[k * HH + col1];
        const unsigned int w2a = *(const unsigned int*)(Wr2 + (size_t)(k * HH + col0) * 2);
        const unsigned int w2b = *(const unsigned int*)(Wr2 + (size_t)(k * HH + col1) * 2);
        const float w200 = bf2f((unsigned short)0) , dummy = 0.f; // placeholder removed below
        (void)w200; (void)dummy;
        const float wa0 = ((const float*)&w2a)[0] * 0.f; (void)wa0; // (avoid misuse)
        // Wr2 is fp32: load the two floats directly.
        const float v200 = Wr2[(size_t)(k * HH + col0) * 2];
        const float v201 = Wr2[(size_t)(k * HH + col0) * 2 + 1];
        const float v210 = Wr2[(size_t)(k * HH + col1) * 2];
        const float v211 = Wr2[(size_t)(k * HH + col1) * 2 + 1];

#pragma unroll
        for (int mt = 0; mt < 2; ++mt) {
            f32x16 aN0 = mt ? acc10 : acc00;
            f32x16 aN1 = mt ? acc11 : acc01;
            float p0[16], p1[16];
#pragma unroll
            for (int reg = 0; reg < 16; ++reg) {
                float rv0 = gelu_cheap(aN0[reg] + bb0);
                float rv1 = gelu_cheap(aN1[reg] + bb1v);
                p0[reg] = fmaf(rv0, v200, rv1 * v210);
                p1[reg] = fmaf(rv0, v201, rv1 * v211);
            }
#pragma unroll
            for (int off = 1; off < 32; off <<= 1) {
#pragma unroll
                for (int reg = 0; reg < 16; ++reg) {
                    p0[reg] += __shfl_xor(p0[reg], off);
                    p1[reg] += __shfl_xor(p1[reg], off);
                }
            }
            if (lane31 == 0) {
#pragma unroll
                for (int reg = 0; reg < 16; ++reg) {
                    int row = mt * 32 + (reg & 3) + 8 * (reg >> 2) + 4 * hf;
                    atomicAdd(&po[row][0], p0[reg]);
                    atomicAdd(&po[row][1], p1[reg]);
                }
            }
        }
    }
    __syncthreads();

    if (tid < TO) {
        int t = tid >> 1, o = tid & 1;
        float v = coarse[tid] + po[t][o] + br2[k * 2 + o];
        pred_out[((b * KK + k) * TT + t) * 2 + o] = v;
    }
}

// ---------------- softmax over K for mode_probs ----------------
__global__ void k_softmax(const float* __restrict__ conf, float* __restrict__ out) {
    int b = blockIdx.x * blockDim.x + threadIdx.x;
    if (b < BB) {
        float v[KK];
        float m = -1e30f;
        for (int i = 0; i < KK; ++i) { v[i] = conf[b * KK + i]; m = fmaxf(m, v[i]); }
        float s = 0.f;
        for (int i = 0; i < KK; ++i) { v[i] = __expf(v[i] - m); s += v[i]; }
        float inv = 1.0f / s;
        for (int i = 0; i < KK; ++i) out[b * KK + i] = v[i] * inv;
    }
}

extern "C" void kernel_launch(void* const* d_in, const int* in_sizes, int n_in,
                              void* d_out, int out_size, void* d_ws, size_t ws_size,
                              hipStream_t stream) {
    const float* I0  = (const float*)d_in[0];
    const float* I1  = (const float*)d_in[1];
    const float* I2  = (const float*)d_in[2];
    const float* MQ  = (const float*)d_in[3];
    const float* Wc1 = (const float*)d_in[4];
    const float* bc1 = (const float*)d_in[5];
    const float* Wc2 = (const float*)d_in[6];
    const float* bc2 = (const float*)d_in[7];
    const float* Wk1 = (const float*)d_in[8];
    const float* bk1 = (const float*)d_in[9];
    const float* Wk2 = (const float*)d_in[10];
    const float* bk2 = (const float*)d_in[11];
    const float* Wt  = (const float*)d_in[12];
    const float* bt  = (const float*)d_in[13];
    const float* Wv  = (const float*)d_in[18];
    const float* bv  = (const float*)d_in[19];
    const float* Wo  = (const float*)d_in[20];
    const float* bo  = (const float*)d_in[21];
    const float* lng = (const float*)d_in[22];
    const float* lnb = (const float*)d_in[23];
    const float* Wr1 = (const float*)d_in[24];
    const float* br1 = (const float*)d_in[25];
    const float* Wr2 = (const float*)d_in[26];
    const float* br2 = (const float*)d_in[27];
    const float* Wf1 = (const float*)d_in[28];
    const float* bf1 = (const float*)d_in[29];
    const float* Wf2 = (const float*)d_in[30];
    const float* bf2v = (const float*)d_in[31];

    unsigned short* wsu   = (unsigned short*)d_ws;
    unsigned short* wc1t  = wsu;                 // 786,432   [512][1536]
    unsigned short* wc2t  = wsu + 786432;        // 262,144
    unsigned short* wvt   = wsu + 1048576;       // 262,144
    unsigned short* wot   = wsu + 1310720;       // 262,144
    unsigned short* wk1t  = wsu + 1572864;       // 3,145,728 (K)[1024][512]
    unsigned short* wk2t  = wsu + 4718592;       // 737,280   (K)[120][1024]
    unsigned short* wf1t  = wsu + 5455872;       // 32,768    [64][512]
    unsigned short* wr1t  = wsu + 5488640;       // 1,572,864 (K)[512][512]
    unsigned short* ctx   = wsu + 7061504;       // 262,144
    unsigned short* attn  = wsu + 7323648;       // 262,144
    unsigned short* tmp   = wsu + 7585792;       // 262,144 (g1 / vbuf)
    unsigned short* coarse= wsu + 7847936;       // 368,640 (B,K,120)
    float* conf = (float*)(wsu + 8216576);       // 3072 fp32

    float* pred = (float*)d_out;
    float* probs = pred + BB * KK * TT * OO;

    // -- prep: all weights -> bf16 [n][f], single launch --
    TD8 td;
    td.e[0] = {Wc1, wc1t, 3 * HH, HH, 48 * 16};
    td.e[1] = {Wc2, wc2t, HH, HH, 16 * 16};
    td.e[2] = {Wv,  wvt,  HH, HH, 16 * 16};
    td.e[3] = {Wo,  wot,  HH, HH, 16 * 16};
    td.e[4] = {Wk1, wk1t, HH, H2, 16 * 32 * 6};
    td.e[5] = {Wk2, wk2t, H2, TO, 32 * 4 * 6};
    td.e[6] = {Wf1, wf1t, HH, 64, 16 * 2};
    td.e[7] = {Wr1, wr1t, HH, HH, 16 * 16 * 6};
    int total_tiles = 768 + 256 * 3 + 3072 + 768 + 32 + 1536;
    k_trans_all<<<dim3(total_tiles), 256, 0, stream>>>(td);

    // -- ctx chain --
    k_gemm_m<true,  true ><<<dim3(16, 8), 256, 0, stream>>>(I0, I1, I2, wc1t, bc1, tmp, 3 * HH);
    k_gemm_m<false, false><<<dim3(16, 8), 256, 0, stream>>>(tmp, nullptr, nullptr, wc2t, bc2, ctx, HH);
    k_gemm_m<false, false><<<dim3(16, 8), 256, 0, stream>>>(ctx, nullptr, nullptr, wvt, bv, tmp, HH);
    k_gemm_m<false, false><<<dim3(16, 8), 256, 0, stream>>>(tmp, nullptr, nullptr, wot, bo, attn, HH);

    k_bc<<<dim3(96), 512, 0, stream>>>(ctx, MQ, wk1t, bk1, wk2t, bk2, wf1t, bf1, Wf2, bf2v,
                                       coarse, conf);
    k_ef<<<dim3(BB * KK), 512, 0, stream>>>(attn, coarse, Wt, bt, lng, lnb,
                                            wr1t, br1, Wr2, br2, pred);
    k_softmax<<<dim3(2), 256, 0, stream>>>(conf, probs);
}

// Round 11
// 482.495 us; speedup vs baseline: 2.3833x; 1.0055x over previous
//
#include <hip/hip_runtime.h>
#include <math.h>

#define BB 512
#define HH 512
#define KK 6
#define TT 60
#define OO 2
#define H2 1024
#define TO 120
#define RFP 520   // padded LDS row stride (bf16 elems), 1040B = 65x16B
#define HSP 1032  // padded h row stride (bf16 elems)

typedef __bf16 bf16x8 __attribute__((ext_vector_type(8)));
typedef float  f32x4  __attribute__((ext_vector_type(4)));
typedef float  f32x16 __attribute__((ext_vector_type(16)));

__device__ __forceinline__ float bf2f(unsigned short u) {
    union { unsigned int i; float f; } v; v.i = ((unsigned int)u) << 16; return v.f;
}
__device__ __forceinline__ unsigned short f2bf(float f) {
    union { float f; unsigned int i; } v; v.f = f;
    unsigned int b = v.i;
    return (unsigned short)((b + 0x7FFFu + ((b >> 16) & 1u)) >> 16); // RNE
}
__device__ __forceinline__ float gelu_exact(float x) {
    return 0.5f * x * (1.0f + erff(x * 0.70710678118654752f));
}

#if defined(__has_builtin)
#  if __has_builtin(__builtin_amdgcn_rcpf)
#    define FAST_RCP(x) __builtin_amdgcn_rcpf(x)
#  endif
#  if __has_builtin(__builtin_amdgcn_exp2f)
#    define FAST_EXP2(x) __builtin_amdgcn_exp2f(x)
#  endif
#endif
#ifndef FAST_RCP
#  define FAST_RCP(x) (1.0f / (x))
#endif
#ifndef FAST_EXP2
#  define FAST_EXP2(x) __expf((x) * 0.69314718056f)
#endif

// tanh-form GELU, constants pre-scaled by log2(e); ~7 VALU inst, err ~3e-4.
__device__ __forceinline__ float gelu_cheap(float x) {
    float x2 = x * x;
    float z = x * fmaf(0.10294324f, x2, 2.3022082f);
    float e = FAST_EXP2(-z);
    return x * FAST_RCP(1.0f + e);
}

struct F8 { float v[8]; };
__device__ __forceinline__ F8 load8f(const float* p) {
    F8 r;
    float4 a = *(const float4*)p;
    float4 b = *(const float4*)(p + 4);
    r.v[0] = a.x; r.v[1] = a.y; r.v[2] = a.z; r.v[3] = a.w;
    r.v[4] = b.x; r.v[5] = b.y; r.v[6] = b.z; r.v[7] = b.w;
    return r;
}
__device__ __forceinline__ F8 load8b(const unsigned short* p) {
    ushort4 a = *(const ushort4*)p;
    ushort4 b = *(const ushort4*)(p + 4);
    F8 r;
    r.v[0] = bf2f(a.x); r.v[1] = bf2f(a.y); r.v[2] = bf2f(a.z); r.v[3] = bf2f(a.w);
    r.v[4] = bf2f(b.x); r.v[5] = bf2f(b.y); r.v[6] = bf2f(b.z); r.v[7] = bf2f(b.w);
    return r;
}

// ---- fused transpose: 8 weight tensors fp32 [F][N](xZ) -> bf16 [N][F], one launch ----
struct TD { const float* src; unsigned short* dst; int F, N, tiles; };
struct TD8 { TD e[8]; };

__global__ void k_trans_all(TD8 d) {
    __shared__ unsigned short t[32][33];
    int idx = blockIdx.x;
    int i = 0;
    while (i < 7 && idx >= d.e[i].tiles) { idx -= d.e[i].tiles; ++i; }
    const int F = d.e[i].F, N = d.e[i].N;
    const int tx = F >> 5, ty = (N + 31) >> 5;
    const int per = tx * ty;
    const int z = idx / per; idx -= z * per;
    const int fx = (idx % tx) * 32, ny = (idx / tx) * 32;
    const float* src = d.e[i].src + (size_t)z * F * N;
    unsigned short* dst = d.e[i].dst + (size_t)z * F * N;
    const int r = threadIdx.x / 32, c = threadIdx.x % 32;
#pragma unroll
    for (int q = 0; q < 4; ++q) {
        int fr = fx + r + 8 * q;
        if (ny + c < N) t[r + 8 * q][c] = f2bf(src[(size_t)fr * N + ny + c]);
    }
    __syncthreads();
#pragma unroll
    for (int q = 0; q < 4; ++q) {
        int nr = ny + r + 8 * q;
        if (nr < N) dst[(size_t)nr * F + fx + c] = t[c][r + 8 * q];
    }
}

// --------- MFMA ctx-chain GEMM: C(512x512 bf16) = [gelu](A @ B + bias) ---------
template <bool CONCAT, bool GELU>
__launch_bounds__(256)
__global__ void k_gemm_m(const void* __restrict__ A0, const void* __restrict__ A1,
                         const void* __restrict__ A2, const unsigned short* __restrict__ BT,
                         const float* __restrict__ bias, unsigned short* __restrict__ C,
                         int Kd) {
    __shared__ __align__(16) unsigned short As[32 * RFP];
    const int tid = threadIdx.x;
    const int bm = blockIdx.x * 32;
    const int bn = blockIdx.y * 64;
    const int w = tid >> 6, ln = tid & 63;
    const int lane15 = ln & 15, quad = ln >> 4;
    const int n = bn + w * 16 + lane15;
    const int nchunks = Kd / HH;

    f32x4 acc0 = {0.f, 0.f, 0.f, 0.f}, acc1 = {0.f, 0.f, 0.f, 0.f};

    for (int kc = 0; kc < nchunks; ++kc) {
        {
            int r = tid >> 3, c0 = (tid & 7) * 64;
            unsigned short* dp = As + r * RFP + c0;
            if (CONCAT) {
                const float* src = (kc == 0) ? (const float*)A0
                                 : (kc == 1) ? (const float*)A1 : (const float*)A2;
                const float* sp = src + (bm + r) * HH + c0;
                for (int c = 0; c < 64; c += 8) {
                    F8 v = load8f(sp + c);
                    unsigned int pk[4];
#pragma unroll
                    for (int j = 0; j < 4; ++j)
                        pk[j] = (unsigned int)f2bf(v.v[2 * j]) |
                                ((unsigned int)f2bf(v.v[2 * j + 1]) << 16);
                    *(uint4*)(dp + c) = make_uint4(pk[0], pk[1], pk[2], pk[3]);
                }
            } else {
                const unsigned short* sp = (const unsigned short*)A0 + (bm + r) * HH + c0;
                for (int c = 0; c < 64; c += 8)
                    *(uint4*)(dp + c) = *(const uint4*)(sp + c);
            }
        }
        __syncthreads();
        const unsigned short* bp = BT + (size_t)n * Kd + kc * HH + quad * 8;
        for (int f0 = 0; f0 < HH; f0 += 32) {
            bf16x8 a0 = *(const bf16x8*)(As + lane15 * RFP + f0 + quad * 8);
            bf16x8 a1 = *(const bf16x8*)(As + (16 + lane15) * RFP + f0 + quad * 8);
            bf16x8 bf = *(const bf16x8*)(bp + f0);
            acc0 = __builtin_amdgcn_mfma_f32_16x16x32_bf16(a0, bf, acc0, 0, 0, 0);
            acc1 = __builtin_amdgcn_mfma_f32_16x16x32_bf16(a1, bf, acc1, 0, 0, 0);
        }
        __syncthreads();
    }
    const float bb = bias[n];
#pragma unroll
    for (int reg = 0; reg < 4; ++reg) {
        float v0 = acc0[reg] + bb, v1 = acc1[reg] + bb;
        if (GELU) { v0 = gelu_exact(v0); v1 = gelu_exact(v1); }
        C[(bm + quad * 4 + reg) * HH + n] = f2bf(v0);
        C[(bm + 16 + quad * 4 + reg) * HH + n] = f2bf(v1);
    }
}

// ---------------- k_bc: batched coarse-heads + conf, per (k, 16 b-rows), 8 waves ----------------
__launch_bounds__(512)
__global__ void k_bc(const unsigned short* __restrict__ ctx, const float* __restrict__ mq,
                     const unsigned short* __restrict__ Wk1T, const float* __restrict__ bk1,
                     const unsigned short* __restrict__ Wk2T, const float* __restrict__ bk2,
                     const unsigned short* __restrict__ Wf1T, const float* __restrict__ bf1,
                     const float* __restrict__ Wf2, const float* __restrict__ bf2v,
                     unsigned short* __restrict__ coarse_out, float* __restrict__ conf_out)
{
    __shared__ __align__(16) unsigned short mf[16 * RFP];   // 16,640 B
    __shared__ __align__(16) unsigned short hs[16 * HSP];   // 33,024 B

    const int tid = threadIdx.x;
    const int k = blockIdx.x % KK;
    const int b0 = (blockIdx.x / KK) * 16;
    const int w = tid >> 6;
    const int ln = tid & 63;
    const int lane15 = ln & 15;
    const int quad = ln >> 4;

    // ---- stage mf = bf16(ctx + mq[k]) rows b0..b0+15 ----
    {
        int r = tid >> 5;               // 0..15
        int c0 = (tid & 31) * 16;
        const unsigned short* cp = ctx + (b0 + r) * HH + c0;
        const float* qp = mq + k * HH + c0;
        unsigned short* dp = mf + r * RFP + c0;
        for (int c = 0; c < 16; c += 8) {
            F8 cv = load8b(cp + c);
            F8 qv = load8f(qp + c);
            unsigned int pk[4];
#pragma unroll
            for (int j = 0; j < 4; ++j)
                pk[j] = (unsigned int)f2bf(cv.v[2 * j] + qv.v[2 * j]) |
                        ((unsigned int)f2bf(cv.v[2 * j + 1] + qv.v[2 * j + 1]) << 16);
            *(uint4*)(dp + c) = make_uint4(pk[0], pk[1], pk[2], pk[3]);
        }
    }
    __syncthreads();

    // ---- GEMM1: h = gelu(mf @ Wk1[k] + bk1[k]) -> hs. Per-wave n-slice 128. ----
    {
        const unsigned short* wk1t = Wk1T + (size_t)k * H2 * HH;
        const float* bk1p = bk1 + k * H2;
        for (int g = 0; g < 8; ++g) {
            const int n = w * 128 + g * 16 + lane15;
            f32x4 acc0 = {0.f,0.f,0.f,0.f};
            const unsigned short* bp = wk1t + (size_t)n * HH + quad * 8;
            for (int f0 = 0; f0 < HH; f0 += 32) {
                bf16x8 a0 = *(const bf16x8*)(mf + lane15 * RFP + f0 + quad * 8);
                bf16x8 bf = *(const bf16x8*)(bp + f0);
                acc0 = __builtin_amdgcn_mfma_f32_16x16x32_bf16(a0, bf, acc0, 0, 0, 0);
            }
            const float bias = bk1p[n];
#pragma unroll
            for (int reg = 0; reg < 4; ++reg)
                hs[(quad * 4 + reg) * HSP + n] = f2bf(gelu_exact(acc0[reg] + bias));
        }
    }
    __syncthreads();

    // ---- GEMM2: coarse = h @ Wk2[k] + bk2[k]. Per-wave n-tile 16. ----
    {
        const unsigned short* wk2t = Wk2T + (size_t)k * TO * H2;
        const int n = w * 16 + lane15;
        const int nc = (n < TO) ? n : (TO - 1);
        f32x4 acc0 = {0.f,0.f,0.f,0.f};
        const unsigned short* bp = wk2t + (size_t)nc * H2 + quad * 8;
        for (int f0 = 0; f0 < H2; f0 += 32) {
            bf16x8 a0 = *(const bf16x8*)(hs + lane15 * HSP + f0 + quad * 8);
            bf16x8 bf = *(const bf16x8*)(bp + f0);
            acc0 = __builtin_amdgcn_mfma_f32_16x16x32_bf16(a0, bf, acc0, 0, 0, 0);
        }
        if (n < TO) {
            const float bias = bk2[k * TO + n];
#pragma unroll
            for (int reg = 0; reg < 4; ++reg)
                coarse_out[((b0 + quad * 4 + reg) * KK + k) * TO + n] = f2bf(acc0[reg] + bias);
        }
    }

    // ---- GEMM3 (wave 0): conf = relu(mf @ Wf1 + bf1) @ Wf2 + bf2 ----
    if (w == 0) {
        f32x4 acc[4];
#pragma unroll
        for (int nt = 0; nt < 4; ++nt) { f32x4 z = {0.f,0.f,0.f,0.f}; acc[nt] = z; }
        for (int f0 = 0; f0 < HH; f0 += 32) {
            bf16x8 a0 = *(const bf16x8*)(mf + lane15 * RFP + f0 + quad * 8);
#pragma unroll
            for (int nt = 0; nt < 4; ++nt) {
                const int n = nt * 16 + lane15;
                bf16x8 bf = *(const bf16x8*)(Wf1T + (size_t)n * HH + f0 + quad * 8);
                acc[nt] = __builtin_amdgcn_mfma_f32_16x16x32_bf16(a0, bf, acc[nt], 0, 0, 0);
            }
        }
        const float b2 = bf2v[0];
#pragma unroll
        for (int reg = 0; reg < 4; ++reg) {
            float s = 0.f;
#pragma unroll
            for (int nt = 0; nt < 4; ++nt) {
                const int n = nt * 16 + lane15;
                s = fmaf(fmaxf(acc[nt][reg] + bf1[n], 0.f), Wf2[n], s);
            }
#pragma unroll
            for (int off = 1; off < 16; off <<= 1) s += __shfl_xor(s, off);
            if (lane15 == 0)
                conf_out[(b0 + quad * 4 + reg) * KK + k] = s + b2;
        }
    }
}

// ---------------- k_ef: per (b,k) traj+LN (Phase E) + refine via 32x32x16 MFMA (Phase F)
//                  ROUND-8-PASSING VERSION (shuffle+atomic po epilogue) ----------------
__launch_bounds__(512, 4)
__global__ void k_ef(
    const unsigned short* __restrict__ attn, const unsigned short* __restrict__ coarse_ws,
    const float* __restrict__ Wt,  const float* __restrict__ bt,
    const float* __restrict__ lng, const float* __restrict__ lnb,
    const unsigned short* __restrict__ Wr1T, const float* __restrict__ br1,
    const float* __restrict__ Wr2, const float* __restrict__ br2,
    float* __restrict__ pred_out)
{
    __shared__ __align__(16) unsigned short rf[64 * RFP];
    __shared__ float coarse[TO];
    __shared__ float po[64][2];

    const int tid = threadIdx.x;
    const int b = blockIdx.x / KK;
    const int k = blockIdx.x % KK;
    const int w = tid >> 6;          // 0..7
    const int ln = tid & 63;

    const unsigned short* attb = attn + b * HH;

    if (tid < TO) coarse[tid] = bf2f(coarse_ws[(b * KK + k) * TO + tid]);
    if (tid >= 128 && tid < 256) ((float*)po)[tid - 128] = 0.f;
    __syncthreads();

    // ---- Phase E: traj=gelu(coarse@Wt+bt); rf = LN(traj+attn)*g+b (bf16) ----
    {
        const int cbase = ln * 8;
        F8 w0 = load8f(Wt + cbase);
        F8 w1 = load8f(Wt + HH + cbase);
        F8 b8 = load8f(bt + cbase);
        F8 g8 = load8f(lng + cbase);
        F8 bb8 = load8f(lnb + cbase);
        F8 a8 = load8b(attb + cbase);
#pragma unroll
        for (int r = 0; r < 8; ++r) {
            int t = w + 8 * r;
            if (t < 60) {
                float co0 = coarse[2 * t], co1 = coarse[2 * t + 1];
                float x[8]; float s = 0.f, s2 = 0.f;
#pragma unroll
                for (int j = 0; j < 8; ++j) {
                    float vv = fmaf(co0, w0.v[j], fmaf(co1, w1.v[j], b8.v[j]));
                    vv = gelu_cheap(vv) + a8.v[j];
                    x[j] = vv; s += vv; s2 = fmaf(vv, vv, s2);
                }
#pragma unroll
                for (int off = 32; off > 0; off >>= 1) {
                    s += __shfl_xor(s, off);
                    s2 += __shfl_xor(s2, off);
                }
                float mean = s * (1.0f / HH);
                float var = fmaf(-mean, mean, s2 * (1.0f / HH));
                float inv = rsqrtf(var + 1e-5f);
                unsigned int pk[4];
#pragma unroll
                for (int j = 0; j < 4; ++j) {
                    float y0 = fmaf((x[2 * j] - mean) * inv, g8.v[2 * j], bb8.v[2 * j]);
                    float y1 = fmaf((x[2 * j + 1] - mean) * inv, g8.v[2 * j + 1], bb8.v[2 * j + 1]);
                    pk[j] = (unsigned int)f2bf(y0) | ((unsigned int)f2bf(y1) << 16);
                }
                *(uint4*)(rf + t * RFP + cbase) = make_uint4(pk[0], pk[1], pk[2], pk[3]);
            } else {
                *(uint4*)(rf + t * RFP + cbase) = make_uint4(0, 0, 0, 0);
            }
        }
    }
    __syncthreads();

    // ---- Phase F: r=gelu(rf@Wr1+br1); offsets=r@Wr2  (32x32x16 MFMA) ----
    // A[m=lane&31][k=hf*8+j], B[n=lane&31][k=hf*8+j],
    // C/D col=lane&31, row=(reg&3)+8*(reg>>2)+4*hf  [m74/m101]
    {
        const unsigned short* wr1t_k = Wr1T + (size_t)k * HH * HH;
        const int lane31 = ln & 31;
        const int hf = ln >> 5;
        const int n0 = w * 64;
        const unsigned short* a0p = rf + lane31 * RFP + hf * 8;
        const unsigned short* a1p = a0p + 32 * RFP;
        const unsigned short* b0p = wr1t_k + (size_t)(n0 + lane31) * HH + hf * 8;
        const unsigned short* b1p = b0p + (size_t)32 * HH;

        f32x16 acc00 = {0.f,0.f,0.f,0.f,0.f,0.f,0.f,0.f,0.f,0.f,0.f,0.f,0.f,0.f,0.f,0.f};
        f32x16 acc01 = acc00, acc10 = acc00, acc11 = acc00;

#pragma unroll 2
        for (int k0 = 0; k0 < HH; k0 += 16) {
            bf16x8 A0 = *(const bf16x8*)(a0p + k0);
            bf16x8 A1 = *(const bf16x8*)(a1p + k0);
            bf16x8 B0 = *(const bf16x8*)(b0p + k0);
            bf16x8 B1 = *(const bf16x8*)(b1p + k0);
            acc00 = __builtin_amdgcn_mfma_f32_32x32x16_bf16(A0, B0, acc00, 0, 0, 0);
            acc01 = __builtin_amdgcn_mfma_f32_32x32x16_bf16(A0, B1, acc01, 0, 0, 0);
            acc10 = __builtin_amdgcn_mfma_f32_32x32x16_bf16(A1, B0, acc10, 0, 0, 0);
            acc11 = __builtin_amdgcn_mfma_f32_32x32x16_bf16(A1, B1, acc11, 0, 0, 0);
        }

        const int col0 = n0 + lane31;
        const int col1 = col0 + 32;
        const float bb0 = br1[k * HH + col0];
        const float bb1v = br1[k * HH + col1];
        const float v200 = Wr2[(size_t)(k * HH + col0) * 2];
        const float v201 = Wr2[(size_t)(k * HH + col0) * 2 + 1];
        const float v210 = Wr2[(size_t)(k * HH + col1) * 2];
        const float v211 = Wr2[(size_t)(k * HH + col1) * 2 + 1];

#pragma unroll
        for (int mt = 0; mt < 2; ++mt) {
            f32x16 aN0 = mt ? acc10 : acc00;
            f32x16 aN1 = mt ? acc11 : acc01;
            float p0[16], p1[16];
#pragma unroll
            for (int reg = 0; reg < 16; ++reg) {
                float rv0 = gelu_cheap(aN0[reg] + bb0);
                float rv1 = gelu_cheap(aN1[reg] + bb1v);
                p0[reg] = fmaf(rv0, v200, rv1 * v210);
                p1[reg] = fmaf(rv0, v201, rv1 * v211);
            }
#pragma unroll
            for (int off = 1; off < 32; off <<= 1) {
#pragma unroll
                for (int reg = 0; reg < 16; ++reg) {
                    p0[reg] += __shfl_xor(p0[reg], off);
                    p1[reg] += __shfl_xor(p1[reg], off);
                }
            }
            if (lane31 == 0) {
#pragma unroll
                for (int reg = 0; reg < 16; ++reg) {
                    int row = mt * 32 + (reg & 3) + 8 * (reg >> 2) + 4 * hf;
                    atomicAdd(&po[row][0], p0[reg]);
                    atomicAdd(&po[row][1], p1[reg]);
                }
            }
        }
    }
    __syncthreads();

    if (tid < TO) {
        int t = tid >> 1, o = tid & 1;
        float v = coarse[tid] + po[t][o] + br2[k * 2 + o];
        pred_out[((b * KK + k) * TT + t) * 2 + o] = v;
    }
}

// ---------------- softmax over K for mode_probs ----------------
__global__ void k_softmax(const float* __restrict__ conf, float* __restrict__ out) {
    int b = blockIdx.x * blockDim.x + threadIdx.x;
    if (b < BB) {
        float v[KK];
        float m = -1e30f;
        for (int i = 0; i < KK; ++i) { v[i] = conf[b * KK + i]; m = fmaxf(m, v[i]); }
        float s = 0.f;
        for (int i = 0; i < KK; ++i) { v[i] = __expf(v[i] - m); s += v[i]; }
        float inv = 1.0f / s;
        for (int i = 0; i < KK; ++i) out[b * KK + i] = v[i] * inv;
    }
}

extern "C" void kernel_launch(void* const* d_in, const int* in_sizes, int n_in,
                              void* d_out, int out_size, void* d_ws, size_t ws_size,
                              hipStream_t stream) {
    const float* I0  = (const float*)d_in[0];
    const float* I1  = (const float*)d_in[1];
    const float* I2  = (const float*)d_in[2];
    const float* MQ  = (const float*)d_in[3];
    const float* Wc1 = (const float*)d_in[4];
    const float* bc1 = (const float*)d_in[5];
    const float* Wc2 = (const float*)d_in[6];
    const float* bc2 = (const float*)d_in[7];
    const float* Wk1 = (const float*)d_in[8];
    const float* bk1 = (const float*)d_in[9];
    const float* Wk2 = (const float*)d_in[10];
    const float* bk2 = (const float*)d_in[11];
    const float* Wt  = (const float*)d_in[12];
    const float* bt  = (const float*)d_in[13];
    const float* Wv  = (const float*)d_in[18];
    const float* bv  = (const float*)d_in[19];
    const float* Wo  = (const float*)d_in[20];
    const float* bo  = (const float*)d_in[21];
    const float* lng = (const float*)d_in[22];
    const float* lnb = (const float*)d_in[23];
    const float* Wr1 = (const float*)d_in[24];
    const float* br1 = (const float*)d_in[25];
    const float* Wr2 = (const float*)d_in[26];
    const float* br2 = (const float*)d_in[27];
    const float* Wf1 = (const float*)d_in[28];
    const float* bf1 = (const float*)d_in[29];
    const float* Wf2 = (const float*)d_in[30];
    const float* bf2v = (const float*)d_in[31];

    unsigned short* wsu   = (unsigned short*)d_ws;
    unsigned short* wc1t  = wsu;                 // 786,432   [512][1536]
    unsigned short* wc2t  = wsu + 786432;        // 262,144
    unsigned short* wvt   = wsu + 1048576;       // 262,144
    unsigned short* wot   = wsu + 1310720;       // 262,144
    unsigned short* wk1t  = wsu + 1572864;       // 3,145,728 (K)[1024][512]
    unsigned short* wk2t  = wsu + 4718592;       // 737,280   (K)[120][1024]
    unsigned short* wf1t  = wsu + 5455872;       // 32,768    [64][512]
    unsigned short* wr1t  = wsu + 5488640;       // 1,572,864 (K)[512][512]
    unsigned short* ctx   = wsu + 7061504;       // 262,144
    unsigned short* attn  = wsu + 7323648;       // 262,144
    unsigned short* tmp   = wsu + 7585792;       // 262,144 (g1 / vbuf)
    unsigned short* coarse= wsu + 7847936;       // 368,640 (B,K,120)
    float* conf = (float*)(wsu + 8216576);       // 3072 fp32

    float* pred = (float*)d_out;
    float* probs = pred + BB * KK * TT * OO;

    // -- prep: all weights -> bf16 [n][f], single launch --
    TD8 td;
    td.e[0] = {Wc1, wc1t, 3 * HH, HH, 768};
    td.e[1] = {Wc2, wc2t, HH, HH, 256};
    td.e[2] = {Wv,  wvt,  HH, HH, 256};
    td.e[3] = {Wo,  wot,  HH, HH, 256};
    td.e[4] = {Wk1, wk1t, HH, H2, 3072};
    td.e[5] = {Wk2, wk2t, H2, TO, 768};
    td.e[6] = {Wf1, wf1t, HH, 64, 32};
    td.e[7] = {Wr1, wr1t, HH, HH, 1536};
    k_trans_all<<<dim3(6944), 256, 0, stream>>>(td);

    // -- ctx chain --
    k_gemm_m<true,  true ><<<dim3(16, 8), 256, 0, stream>>>(I0, I1, I2, wc1t, bc1, tmp, 3 * HH);
    k_gemm_m<false, false><<<dim3(16, 8), 256, 0, stream>>>(tmp, nullptr, nullptr, wc2t, bc2, ctx, HH);
    k_gemm_m<false, false><<<dim3(16, 8), 256, 0, stream>>>(ctx, nullptr, nullptr, wvt, bv, tmp, HH);
    k_gemm_m<false, false><<<dim3(16, 8), 256, 0, stream>>>(tmp, nullptr, nullptr, wot, bo, attn, HH);

    k_bc<<<dim3(192), 512, 0, stream>>>(ctx, MQ, wk1t, bk1, wk2t, bk2, wf1t, bf1, Wf2, bf2v,
                                        coarse, conf);
    k_ef<<<dim3(BB * KK), 512, 0, stream>>>(attn, coarse, Wt, bt, lng, lnb,
                                            wr1t, br1, Wr2, br2, pred);
    k_softmax<<<dim3(2), 256, 0, stream>>>(conf, probs);
}